// Round 4
// baseline (1295.426 us; speedup 1.0000x reference)
//
#include <hip/hip_runtime.h>

// HeteroGNN on MI355X — round 4: aggregate-first restructure.
//   xs = dinv*(sum dinv*x[nbr] + dinv*x)  (gather on bf16 paired planes)
//   p  = relu(xs@W + x@Wr + mean@Wl + b)  (tri-segment MFMA GEMM, split-bf16)
//   B operands direct-to-register from L2 (no B LDS) -> 32KB LDS, 4 blocks/CU.
// Node features live as u16[N][512]: row = [hi bf16 x256 | lo bf16 x256].

#define DP   256
#define DA   128
#define HIDN 256
#define DOUT 349

typedef unsigned short u16;
typedef __attribute__((ext_vector_type(8))) short bf16x8;
typedef __attribute__((ext_vector_type(4))) float f32x4;

__device__ __forceinline__ u16 bf16_rn(float x) {
  union { float f; unsigned u; } v; v.f = x;
  unsigned r = v.u + 0x7FFFu + ((v.u >> 16) & 1u);
  return (u16)(r >> 16);
}
__device__ __forceinline__ float bf16f(u16 h) {
  union { float f; unsigned u; } v; v.u = ((unsigned)h) << 16; return v.f;
}
__device__ __forceinline__ void split2(float x, u16& h, u16& l) {
  h = bf16_rn(x);
  l = bf16_rn(x - bf16f(h));
}

__device__ __forceinline__ void gload16(const void* g, void* lds) {
  __builtin_amdgcn_global_load_lds(
      (const __attribute__((address_space(1))) unsigned int*)g,
      (__attribute__((address_space(3))) unsigned int*)lds, 16, 0, 0);
}

// ---------------- histogram ----------------
__global__ void hist_kernel(const int* __restrict__ c_dst, const int* __restrict__ w_dst,
                            int* __restrict__ deg_c, int* __restrict__ cnt_w, int e) {
  int i = blockIdx.x * blockDim.x + threadIdx.x;
  if (i < e) {
    atomicAdd(&deg_c[c_dst[i]], 1);
    atomicAdd(&cnt_w[w_dst[i]], 1);
  }
}

// ---------------- exclusive scan ----------------
#define SCAN_TPB 256
#define SCAN_VPT 8
#define SCAN_TILE 2048

__global__ void scan_local(const int* __restrict__ in, int* __restrict__ out,
                           int* __restrict__ bsum, int n) {
  __shared__ int sdata[SCAN_TPB];
  int t = threadIdx.x;
  int base = blockIdx.x * SCAN_TILE + t * SCAN_VPT;
  int v[SCAN_VPT];
  int sum = 0;
#pragma unroll
  for (int j = 0; j < SCAN_VPT; ++j) {
    int idx = base + j;
    v[j] = (idx < n) ? in[idx] : 0;
    sum += v[j];
  }
  sdata[t] = sum;
  __syncthreads();
  for (int off = 1; off < SCAN_TPB; off <<= 1) {
    int x = (t >= off) ? sdata[t - off] : 0;
    __syncthreads();
    sdata[t] += x;
    __syncthreads();
  }
  int prefix = sdata[t] - sum;
  if (t == SCAN_TPB - 1) bsum[blockIdx.x] = sdata[t];
  int run = prefix;
#pragma unroll
  for (int j = 0; j < SCAN_VPT; ++j) {
    int idx = base + j;
    if (idx < n) out[idx] = run;
    run += v[j];
  }
}

__global__ void scan_spine(int* __restrict__ bsum, int nb) {
  __shared__ int sdata[256];
  int t = threadIdx.x;
  int v = (t < nb) ? bsum[t] : 0;
  sdata[t] = v;
  __syncthreads();
  for (int off = 1; off < 256; off <<= 1) {
    int x = (t >= off) ? sdata[t - off] : 0;
    __syncthreads();
    sdata[t] += x;
    __syncthreads();
  }
  if (t < nb) bsum[t] = sdata[t] - v;
}

__global__ void scan_add(int* __restrict__ out, const int* __restrict__ bsum, int n) {
  int add = bsum[blockIdx.x];
  int base = blockIdx.x * SCAN_TILE + threadIdx.x * SCAN_VPT;
#pragma unroll
  for (int j = 0; j < SCAN_VPT; ++j) {
    int idx = base + j;
    if (idx < n) out[idx] += add;
  }
}

// ---------------- CSR fill ----------------
__global__ void fill_csr(const int* __restrict__ c_src, const int* __restrict__ c_dst,
                         const int* __restrict__ w_src, const int* __restrict__ w_dst,
                         int* __restrict__ cur_c, int* __restrict__ cur_w,
                         int* __restrict__ c_sorted, int* __restrict__ w_sorted, int e) {
  int i = blockIdx.x * blockDim.x + threadIdx.x;
  if (i < e) {
    int d = c_dst[i];
    int pos = atomicAdd(&cur_c[d], 1);
    c_sorted[pos] = c_src[i];
    int d2 = w_dst[i];
    int pos2 = atomicAdd(&cur_w[d2], 1);
    w_sorted[pos2] = w_src[i];
  }
}

// ---------------- node prep: dinv + author-mean -> paired bf16 [N][256] -------
__global__ void node_prep(const float* __restrict__ x_author,
                          const int* __restrict__ w_off, const int* __restrict__ w_cnt,
                          const int* __restrict__ w_sorted,
                          const int* __restrict__ deg_c,
                          u16* __restrict__ mean, float* __restrict__ dinv, int n) {
  int wave = (blockIdx.x * blockDim.x + threadIdx.x) >> 6;
  int lane = threadIdx.x & 63;
  if (wave >= n) return;
  int d = wave;
  int start = w_off[d];
  int cnt = w_cnt[d];
  float ax = 0.f, ay = 0.f;
  const float2* xa = (const float2*)x_author;
  for (int j0 = 0; j0 < cnt; j0 += 64) {
    int nn = cnt - j0; nn = nn < 64 ? nn : 64;
    int sl = (j0 + lane < cnt) ? w_sorted[start + j0 + lane] : 0;
    for (int jj = 0; jj < nn; ++jj) {
      int s = __shfl(sl, jj);
      float2 v = xa[(size_t)s * (DA / 2) + lane];
      ax += v.x;
      ay += v.y;
    }
  }
  float inv = 1.0f / (float)((cnt > 0) ? cnt : 1);
  float mx = ax * inv, my = ay * inv;
  u16 h0, l0, h1, l1;
  split2(mx, h0, l0);
  split2(my, h1, l1);
  *(unsigned*)&mean[(size_t)d * 256 + 2 * lane] = (unsigned)h0 | ((unsigned)h1 << 16);
  *(unsigned*)&mean[(size_t)d * 256 + 128 + 2 * lane] = (unsigned)l0 | ((unsigned)l1 << 16);
  if (lane == 0) dinv[d] = rsqrtf((float)(deg_c[d] + 1));
}

// ---------------- x_paper f32 -> paired planes [N][512] ----------------
__global__ void conv_split(const float* __restrict__ x, u16* __restrict__ xp, int n8) {
  int i = blockIdx.x * blockDim.x + threadIdx.x;
  if (i >= n8) return;
  int row = i >> 5, e0 = (i & 31) * 8;
  const float4* x4 = (const float4*)x;
  float4 v0 = x4[(size_t)i * 2];
  float4 v1 = x4[(size_t)i * 2 + 1];
  float vv[8] = {v0.x, v0.y, v0.z, v0.w, v1.x, v1.y, v1.z, v1.w};
  union { u16 u[8]; uint4 v; } H, L;
#pragma unroll
  for (int j = 0; j < 8; ++j) split2(vv[j], H.u[j], L.u[j]);
  *(uint4*)&xp[(size_t)row * 512 + e0] = H.v;
  *(uint4*)&xp[(size_t)row * 512 + 256 + e0] = L.v;
}

// ---------------- weight prep: W[K][N] -> Bt[2][Npad][K] hi/lo ----------------
__global__ void prep_weight(const float* __restrict__ W, int K, int N, int Npad,
                            u16* __restrict__ Bt) {
  int idx = blockIdx.x * blockDim.x + threadIdx.x;
  int tot = Npad * K;
  if (idx >= tot) return;
  int n = idx / K, k = idx - n * K;
  float v = (n < N) ? W[(size_t)k * N + n] : 0.f;
  u16 h, l;
  split2(v, h, l);
  Bt[idx] = h;
  Bt[tot + idx] = l;
}

__global__ void add_bias(const float* __restrict__ a, const float* __restrict__ b,
                         float* __restrict__ o, int n) {
  int i = blockIdx.x * blockDim.x + threadIdx.x;
  if (i < n) o[i] = a[i] + b[i];
}

// ---------------- GCN feature-space aggregation (wave per node) ----------------
// xout[d] = dinv[d]*( sum_{s in N(d)} dinv[s]*x[s] + dinv[d]*x[d] ), paired planes.
// lanes 0-31 accumulate the hi-stream, 32-63 the lo-stream; one xor-32 swap merges.
__global__ void agg_gcn(const u16* __restrict__ xin, const float* __restrict__ dinv,
                        const int* __restrict__ c_off, const int* __restrict__ c_cnt,
                        const int* __restrict__ c_sorted,
                        u16* __restrict__ xout, int n) {
  int wave = (blockIdx.x * blockDim.x + threadIdx.x) >> 6;
  int lane = threadIdx.x & 63;
  if (wave >= n) return;
  int d = wave;
  int start = c_off[d], cnt = c_cnt[d];
  float acc[8] = {};
  const uint4* base = (const uint4*)xin;  // row stride = 64 uint4 (1KB)
  for (int j0 = 0; j0 < cnt; j0 += 64) {
    int nn = cnt - j0; nn = nn < 64 ? nn : 64;
    int sl = (j0 + lane < cnt) ? c_sorted[start + j0 + lane] : 0;
    for (int jj = 0; jj < nn; ++jj) {
      int s = __shfl(sl, jj);
      float ds = dinv[s];
      uint4 v = base[(size_t)s * 64 + lane];
      const u16* pv = (const u16*)&v;
#pragma unroll
      for (int e = 0; e < 8; ++e) acc[e] = fmaf(bf16f(pv[e]), ds, acc[e]);
    }
  }
  float dd = dinv[d];
  {
    uint4 v = base[(size_t)d * 64 + lane];
    const u16* pv = (const u16*)&v;
#pragma unroll
    for (int e = 0; e < 8; ++e) acc[e] = fmaf(bf16f(pv[e]), dd, acc[e]);
  }
  union { u16 u[8]; uint4 v; } O;
#pragma unroll
  for (int e = 0; e < 8; ++e) {
    float full = (acc[e] + __shfl_xor(acc[e], 32)) * dd;
    u16 h = bf16_rn(full);
    O.u[e] = (lane < 32) ? h : bf16_rn(full - bf16f(h));
  }
  ((uint4*)xout)[(size_t)d * 64 + lane] = O.v;
}

// ---------------- tri-segment split-bf16 MFMA GEMM ----------------
// C tile 128x64, 4 waves (2x2). A from paired planes via gload_lds dbuf (32KB).
// B fragments loaded direct global->VGPR (L2-resident weights).
// NSEG=3: C = A0@B0 + A1@B1 + A2@B2(K=128) + bias -> relu -> paired bf16 out.
// NSEG=1: C = A0@B0 + bias -> f32 out (col-checked vs N).
template <int NSEG, bool F32OUT, int GY>
__global__ __launch_bounds__(256, 4) void gemm_mfma(
    const u16* __restrict__ A0, const u16* __restrict__ A1, const u16* __restrict__ A2,
    const u16* __restrict__ B0, const u16* __restrict__ B1, const u16* __restrict__ B2,
    int bs0, int bs1, int bs2,
    const float* __restrict__ bias,
    u16* __restrict__ Cp, float* __restrict__ Cf,
    int M, int N) {
  __shared__ u16 Ah[2][4096], Al[2][4096];

  const int t = threadIdx.x;
  const int wid = t >> 6, lane = t & 63;
  const int wr = wid >> 1, wc = wid & 1;
  const int lrow = lane & 15, kslot = lane >> 4;
  const int jsw = kslot ^ ((lrow >> 1) & 3);

  // bijective XCD-chunked block swizzle (m204), column-tile-fastest
  const int nb = gridDim.x;
  const int q = nb >> 3, r = nb & 7;
  const int xcd = blockIdx.x & 7, pos = blockIdx.x >> 3;
  const int lin = (xcd < r ? xcd * (q + 1) : r * (q + 1) + (xcd - r) * q) + pos;
  const int bx = lin / GY, by = lin - bx * GY;
  const int gm = bx * 128;
  const int gn = by * 64;

  const int s_r = lane >> 2;
  const int s_j = (lane & 3) ^ ((s_r >> 1) & 3);

  f32x4 acc[4][2];
  const f32x4 z4 = {0.f, 0.f, 0.f, 0.f};
#pragma unroll
  for (int m = 0; m < 4; ++m) { acc[m][0] = z4; acc[m][1] = z4; }

  const int NT = (NSEG == 3) ? 20 : 8;

  auto STAGE = [&](int tt, int half) {
    const int seg = tt >> 3;
    const int k0 = (tt & 7) * 32;
    const u16* A;
    int rs;
    if (NSEG == 1 || seg == 0) { A = A0; rs = 512; }
    else if (seg == 1)         { A = A1; rs = 512; }
    else                       { A = A2; rs = 256; }
    const int hoff = rs >> 1;
    const int c = wid * 2;
#pragma unroll
    for (int cc = 0; cc < 2; ++cc) {
      int grow = gm + (c + cc) * 16 + s_r;
      grow = grow < M ? grow : M - 1;
      size_t go = (size_t)grow * rs + (k0 + s_j * 8);
      gload16(A + go, &Ah[half][(c + cc) * 512]);
      gload16(A + go + hoff, &Al[half][(c + cc) * 512]);
    }
  };

  STAGE(0, 0);
  __syncthreads();

  for (int tt = 0; tt < NT; ++tt) {
    const int half = tt & 1;
    if (tt + 1 < NT) STAGE(tt + 1, half ^ 1);

    const int seg = tt >> 3;
    const int k0 = (tt & 7) * 32;
    const u16* B;
    int K, bs;
    if (NSEG == 1 || seg == 0) { B = B0; K = 256; bs = bs0; }
    else if (seg == 1)         { B = B1; K = 256; bs = bs1; }
    else                       { B = B2; K = 128; bs = bs2; }

    // B fragments: direct global loads (L2-hit weights)
    size_t bo = (size_t)(gn + wc * 32 + lrow) * K + (k0 + kslot * 8);
    bf16x8 bh0 = *(const bf16x8*)(B + bo);
    bf16x8 bh1 = *(const bf16x8*)(B + bo + (size_t)16 * K);
    bf16x8 bl0 = *(const bf16x8*)(B + bs + bo);
    bf16x8 bl1 = *(const bf16x8*)(B + bs + bo + (size_t)16 * K);

    bf16x8 ah[4], al[4];
    const int ab = (wr * 64 + lrow) * 32 + jsw * 8;
#pragma unroll
    for (int m = 0; m < 4; ++m) {
      ah[m] = *(const bf16x8*)&Ah[half][ab + m * 512];
      al[m] = *(const bf16x8*)&Al[half][ab + m * 512];
    }
#pragma unroll
    for (int m = 0; m < 4; ++m) {
      acc[m][0] = __builtin_amdgcn_mfma_f32_16x16x32_bf16(ah[m], bh0, acc[m][0], 0, 0, 0);
      acc[m][0] = __builtin_amdgcn_mfma_f32_16x16x32_bf16(al[m], bh0, acc[m][0], 0, 0, 0);
      acc[m][0] = __builtin_amdgcn_mfma_f32_16x16x32_bf16(ah[m], bl0, acc[m][0], 0, 0, 0);
      acc[m][1] = __builtin_amdgcn_mfma_f32_16x16x32_bf16(ah[m], bh1, acc[m][1], 0, 0, 0);
      acc[m][1] = __builtin_amdgcn_mfma_f32_16x16x32_bf16(al[m], bh1, acc[m][1], 0, 0, 0);
      acc[m][1] = __builtin_amdgcn_mfma_f32_16x16x32_bf16(ah[m], bl1, acc[m][1], 0, 0, 0);
    }
    __syncthreads();
  }

  // ---- epilogue ----
  const int col0 = gn + wc * 32 + lrow;
  const int row00 = gm + wr * 64 + kslot * 4;
#pragma unroll
  for (int m = 0; m < 4; ++m) {
#pragma unroll
    for (int i = 0; i < 4; ++i) {
      int row = row00 + m * 16 + i;
      if (row >= M) continue;
#pragma unroll
      for (int n = 0; n < 2; ++n) {
        int col = col0 + n * 16;
        float bv = (col < N) ? bias[col] : 0.f;
        float v = acc[m][n][i] + bv;
        if (F32OUT) {
          if (col < N) Cf[(size_t)row * N + col] = v;
        } else {
          v = fmaxf(v, 0.f);
          u16 h, l;
          split2(v, h, l);
          Cp[(size_t)row * 512 + col] = h;
          Cp[(size_t)row * 512 + 256 + col] = l;
        }
      }
    }
  }
}

// ---------------- launch ----------------
static inline size_t align_up(size_t x) { return (x + 255) & ~(size_t)255; }

extern "C" void kernel_launch(void* const* d_in, const int* in_sizes, int n_in,
                              void* d_out, int out_size, void* d_ws, size_t ws_size,
                              hipStream_t stream) {
  const float* x_paper  = (const float*)d_in[0];
  const float* x_author = (const float*)d_in[1];
  const int*   cites    = (const int*)d_in[2];
  const int*   w_src    = (const int*)d_in[3];
  const int*   w_dst    = (const int*)d_in[4];
  const float* W1  = (const float*)d_in[5];
  const float* b1  = (const float*)d_in[6];
  const float* Wl1 = (const float*)d_in[7];
  const float* bl1 = (const float*)d_in[8];
  const float* Wr1 = (const float*)d_in[9];
  const float* W2  = (const float*)d_in[10];
  const float* b2  = (const float*)d_in[11];
  const float* Wl2 = (const float*)d_in[12];
  const float* bl2 = (const float*)d_in[13];
  const float* Wr2 = (const float*)d_in[14];
  const float* linW = (const float*)d_in[15];
  const float* linb = (const float*)d_in[16];
  float* out = (float*)d_out;

  const int N = in_sizes[0] / DP;  // 100000
  const int E = in_sizes[3];       // 1000000
  const int* c_src = cites;
  const int* c_dst = cites + E;

  char* w = (char*)d_ws;
  size_t off = 0;
  auto alloc = [&](size_t bytes) -> void* {
    void* p = w + off;
    off = align_up(off + bytes);
    return p;
  };
  int* deg_c      = (int*)alloc((size_t)N * 4);
  int* cnt_w      = (int*)alloc((size_t)N * 4);
  int* cites_off  = (int*)alloc((size_t)N * 4);
  int* writes_off = (int*)alloc((size_t)N * 4);
  int* cur_c      = (int*)alloc((size_t)N * 4);
  int* cur_w      = (int*)alloc((size_t)N * 4);
  int* bsumA      = (int*)alloc(256 * 4);
  int* bsumB      = (int*)alloc(256 * 4);
  int* c_sorted   = (int*)alloc((size_t)E * 4);
  int* w_sorted   = (int*)alloc((size_t)E * 4);
  float* dinv     = (float*)alloc((size_t)N * 4);
  u16* meanA      = (u16*)alloc((size_t)N * 256 * 2);   // paired [N][256]
  u16* xp         = (u16*)alloc((size_t)N * 512 * 2);   // paired [N][512]
  u16* xs         = (u16*)alloc((size_t)N * 512 * 2);
  u16* pb         = (u16*)alloc((size_t)N * 512 * 2);
  const int bsW = 256 * 256, bsL = 256 * 128, bsLin = 384 * 256;
  u16* BtW1  = (u16*)alloc((size_t)2 * bsW * 2);
  u16* BtWr1 = (u16*)alloc((size_t)2 * bsW * 2);
  u16* BtW2  = (u16*)alloc((size_t)2 * bsW * 2);
  u16* BtWr2 = (u16*)alloc((size_t)2 * bsW * 2);
  u16* BtWl1 = (u16*)alloc((size_t)2 * bsL * 2);
  u16* BtWl2 = (u16*)alloc((size_t)2 * bsL * 2);
  u16* BtLin = (u16*)alloc((size_t)2 * bsLin * 2);
  float* biasR1 = (float*)alloc(HIDN * 4);
  float* biasR2 = (float*)alloc(HIDN * 4);
  (void)ws_size; (void)n_in; (void)out_size;

  hipMemsetAsync(deg_c, 0, (size_t)N * 4, stream);
  hipMemsetAsync(cnt_w, 0, (size_t)N * 4, stream);

  int nbE = (E + 255) / 256;
  hist_kernel<<<nbE, 256, 0, stream>>>(c_dst, w_dst, deg_c, cnt_w, E);

  int nsb = (N + SCAN_TILE - 1) / SCAN_TILE;
  scan_local<<<nsb, SCAN_TPB, 0, stream>>>(deg_c, cites_off, bsumA, N);
  scan_spine<<<1, 256, 0, stream>>>(bsumA, nsb);
  scan_add<<<nsb, SCAN_TPB, 0, stream>>>(cites_off, bsumA, N);
  scan_local<<<nsb, SCAN_TPB, 0, stream>>>(cnt_w, writes_off, bsumB, N);
  scan_spine<<<1, 256, 0, stream>>>(bsumB, nsb);
  scan_add<<<nsb, SCAN_TPB, 0, stream>>>(writes_off, bsumB, N);

  hipMemcpyAsync(cur_c, cites_off, (size_t)N * 4, hipMemcpyDeviceToDevice, stream);
  hipMemcpyAsync(cur_w, writes_off, (size_t)N * 4, hipMemcpyDeviceToDevice, stream);
  fill_csr<<<nbE, 256, 0, stream>>>(c_src, c_dst, w_src, w_dst, cur_c, cur_w,
                                    c_sorted, w_sorted, E);

  // conversions (independent of CSR)
  int n8 = N * 32;
  conv_split<<<(n8 + 255) / 256, 256, 0, stream>>>(x_paper, xp, n8);
  prep_weight<<<(bsW + 255) / 256, 256, 0, stream>>>(W1, 256, 256, 256, BtW1);
  prep_weight<<<(bsW + 255) / 256, 256, 0, stream>>>(Wr1, 256, 256, 256, BtWr1);
  prep_weight<<<(bsW + 255) / 256, 256, 0, stream>>>(W2, 256, 256, 256, BtW2);
  prep_weight<<<(bsW + 255) / 256, 256, 0, stream>>>(Wr2, 256, 256, 256, BtWr2);
  prep_weight<<<(bsL + 255) / 256, 256, 0, stream>>>(Wl1, 128, 256, 256, BtWl1);
  prep_weight<<<(bsL + 255) / 256, 256, 0, stream>>>(Wl2, 128, 256, 256, BtWl2);
  prep_weight<<<(bsLin + 255) / 256, 256, 0, stream>>>(linW, 256, DOUT, 384, BtLin);
  add_bias<<<1, 256, 0, stream>>>(b1, bl1, biasR1, HIDN);
  add_bias<<<1, 256, 0, stream>>>(b2, bl2, biasR2, HIDN);

  int nbWave = (N * 64 + 255) / 256;
  node_prep<<<nbWave, 256, 0, stream>>>(x_author, writes_off, cnt_w, w_sorted,
                                        deg_c, meanA, dinv, N);

  const int GX = (N + 127) / 128;  // 782

  // layer 1
  agg_gcn<<<nbWave, 256, 0, stream>>>(xp, dinv, cites_off, deg_c, c_sorted, xs, N);
  gemm_mfma<3, false, 4><<<GX * 4, 256, 0, stream>>>(
      xs, xp, meanA, BtW1, BtWr1, BtWl1, bsW, bsW, bsL,
      biasR1, pb, nullptr, N, HIDN);
  // layer 2
  agg_gcn<<<nbWave, 256, 0, stream>>>(pb, dinv, cites_off, deg_c, c_sorted, xs, N);
  gemm_mfma<3, false, 4><<<GX * 4, 256, 0, stream>>>(
      xs, pb, meanA, BtW2, BtWr2, BtWl2, bsW, bsW, bsL,
      biasR2, xp, nullptr, N, HIDN);
  // output projection
  gemm_mfma<1, true, 6><<<GX * 6, 256, 0, stream>>>(
      xp, nullptr, nullptr, BtLin, nullptr, nullptr, bsLin, 0, 0,
      linb, nullptr, out, N, DOUT);
}

// Round 5
// 1291.475 us; speedup vs baseline: 1.0031x; 1.0031x over previous
//
#include <hip/hip_runtime.h>

// HeteroGNN on MI355X — round 5: fix B-load vmcnt poisoning via register
// double-buffered B prefetch (B for step tt+1 issued at top of step tt, drained
// by the end-of-step barrier). 4-way unrolled gather loops for load ILP.

#define DP   256
#define DA   128
#define HIDN 256
#define DOUT 349

typedef unsigned short u16;
typedef __attribute__((ext_vector_type(8))) short bf16x8;
typedef __attribute__((ext_vector_type(4))) float f32x4;

__device__ __forceinline__ u16 bf16_rn(float x) {
  union { float f; unsigned u; } v; v.f = x;
  unsigned r = v.u + 0x7FFFu + ((v.u >> 16) & 1u);
  return (u16)(r >> 16);
}
__device__ __forceinline__ float bf16f(u16 h) {
  union { float f; unsigned u; } v; v.u = ((unsigned)h) << 16; return v.f;
}
__device__ __forceinline__ void split2(float x, u16& h, u16& l) {
  h = bf16_rn(x);
  l = bf16_rn(x - bf16f(h));
}

__device__ __forceinline__ void gload16(const void* g, void* lds) {
  __builtin_amdgcn_global_load_lds(
      (const __attribute__((address_space(1))) unsigned int*)g,
      (__attribute__((address_space(3))) unsigned int*)lds, 16, 0, 0);
}

// ---------------- histogram ----------------
__global__ void hist_kernel(const int* __restrict__ c_dst, const int* __restrict__ w_dst,
                            int* __restrict__ deg_c, int* __restrict__ cnt_w, int e) {
  int i = blockIdx.x * blockDim.x + threadIdx.x;
  if (i < e) {
    atomicAdd(&deg_c[c_dst[i]], 1);
    atomicAdd(&cnt_w[w_dst[i]], 1);
  }
}

// ---------------- exclusive scan ----------------
#define SCAN_TPB 256
#define SCAN_VPT 8
#define SCAN_TILE 2048

__global__ void scan_local(const int* __restrict__ in, int* __restrict__ out,
                           int* __restrict__ bsum, int n) {
  __shared__ int sdata[SCAN_TPB];
  int t = threadIdx.x;
  int base = blockIdx.x * SCAN_TILE + t * SCAN_VPT;
  int v[SCAN_VPT];
  int sum = 0;
#pragma unroll
  for (int j = 0; j < SCAN_VPT; ++j) {
    int idx = base + j;
    v[j] = (idx < n) ? in[idx] : 0;
    sum += v[j];
  }
  sdata[t] = sum;
  __syncthreads();
  for (int off = 1; off < SCAN_TPB; off <<= 1) {
    int x = (t >= off) ? sdata[t - off] : 0;
    __syncthreads();
    sdata[t] += x;
    __syncthreads();
  }
  int prefix = sdata[t] - sum;
  if (t == SCAN_TPB - 1) bsum[blockIdx.x] = sdata[t];
  int run = prefix;
#pragma unroll
  for (int j = 0; j < SCAN_VPT; ++j) {
    int idx = base + j;
    if (idx < n) out[idx] = run;
    run += v[j];
  }
}

__global__ void scan_spine(int* __restrict__ bsum, int nb) {
  __shared__ int sdata[256];
  int t = threadIdx.x;
  int v = (t < nb) ? bsum[t] : 0;
  sdata[t] = v;
  __syncthreads();
  for (int off = 1; off < 256; off <<= 1) {
    int x = (t >= off) ? sdata[t - off] : 0;
    __syncthreads();
    sdata[t] += x;
    __syncthreads();
  }
  if (t < nb) bsum[t] = sdata[t] - v;
}

__global__ void scan_add(int* __restrict__ out, const int* __restrict__ bsum, int n) {
  int add = bsum[blockIdx.x];
  int base = blockIdx.x * SCAN_TILE + threadIdx.x * SCAN_VPT;
#pragma unroll
  for (int j = 0; j < SCAN_VPT; ++j) {
    int idx = base + j;
    if (idx < n) out[idx] += add;
  }
}

// ---------------- CSR fill ----------------
__global__ void fill_csr(const int* __restrict__ c_src, const int* __restrict__ c_dst,
                         const int* __restrict__ w_src, const int* __restrict__ w_dst,
                         int* __restrict__ cur_c, int* __restrict__ cur_w,
                         int* __restrict__ c_sorted, int* __restrict__ w_sorted, int e) {
  int i = blockIdx.x * blockDim.x + threadIdx.x;
  if (i < e) {
    int d = c_dst[i];
    int pos = atomicAdd(&cur_c[d], 1);
    c_sorted[pos] = c_src[i];
    int d2 = w_dst[i];
    int pos2 = atomicAdd(&cur_w[d2], 1);
    w_sorted[pos2] = w_src[i];
  }
}

// ---------------- node prep: dinv + author-mean -> paired bf16 [N][256] -------
__global__ void node_prep(const float* __restrict__ x_author,
                          const int* __restrict__ w_off, const int* __restrict__ w_cnt,
                          const int* __restrict__ w_sorted,
                          const int* __restrict__ deg_c,
                          u16* __restrict__ mean, float* __restrict__ dinv, int n) {
  int wave = (blockIdx.x * blockDim.x + threadIdx.x) >> 6;
  int lane = threadIdx.x & 63;
  if (wave >= n) return;
  int d = wave;
  int start = w_off[d];
  int cnt = w_cnt[d];
  float ax = 0.f, ay = 0.f;
  const float2* xa = (const float2*)x_author;
  for (int j0 = 0; j0 < cnt; j0 += 64) {
    int nn = cnt - j0; nn = nn < 64 ? nn : 64;
    int sl = (j0 + lane < cnt) ? w_sorted[start + j0 + lane] : 0;
    int jj = 0;
    for (; jj + 4 <= nn; jj += 4) {
      int s0 = __shfl(sl, jj), s1 = __shfl(sl, jj + 1);
      int s2 = __shfl(sl, jj + 2), s3 = __shfl(sl, jj + 3);
      float2 v0 = xa[(size_t)s0 * (DA / 2) + lane];
      float2 v1 = xa[(size_t)s1 * (DA / 2) + lane];
      float2 v2 = xa[(size_t)s2 * (DA / 2) + lane];
      float2 v3 = xa[(size_t)s3 * (DA / 2) + lane];
      ax += v0.x + v1.x + v2.x + v3.x;
      ay += v0.y + v1.y + v2.y + v3.y;
    }
    for (; jj < nn; ++jj) {
      int s = __shfl(sl, jj);
      float2 v = xa[(size_t)s * (DA / 2) + lane];
      ax += v.x;
      ay += v.y;
    }
  }
  float inv = 1.0f / (float)((cnt > 0) ? cnt : 1);
  float mx = ax * inv, my = ay * inv;
  u16 h0, l0, h1, l1;
  split2(mx, h0, l0);
  split2(my, h1, l1);
  *(unsigned*)&mean[(size_t)d * 256 + 2 * lane] = (unsigned)h0 | ((unsigned)h1 << 16);
  *(unsigned*)&mean[(size_t)d * 256 + 128 + 2 * lane] = (unsigned)l0 | ((unsigned)l1 << 16);
  if (lane == 0) dinv[d] = rsqrtf((float)(deg_c[d] + 1));
}

// ---------------- x_paper f32 -> paired planes [N][512] ----------------
__global__ void conv_split(const float* __restrict__ x, u16* __restrict__ xp, int n8) {
  int i = blockIdx.x * blockDim.x + threadIdx.x;
  if (i >= n8) return;
  int row = i >> 5, e0 = (i & 31) * 8;
  const float4* x4 = (const float4*)x;
  float4 v0 = x4[(size_t)i * 2];
  float4 v1 = x4[(size_t)i * 2 + 1];
  float vv[8] = {v0.x, v0.y, v0.z, v0.w, v1.x, v1.y, v1.z, v1.w};
  union { u16 u[8]; uint4 v; } H, L;
#pragma unroll
  for (int j = 0; j < 8; ++j) split2(vv[j], H.u[j], L.u[j]);
  *(uint4*)&xp[(size_t)row * 512 + e0] = H.v;
  *(uint4*)&xp[(size_t)row * 512 + 256 + e0] = L.v;
}

// ---------------- weight prep: W[K][N] -> Bt[2][Npad][K] hi/lo ----------------
__global__ void prep_weight(const float* __restrict__ W, int K, int N, int Npad,
                            u16* __restrict__ Bt) {
  int idx = blockIdx.x * blockDim.x + threadIdx.x;
  int tot = Npad * K;
  if (idx >= tot) return;
  int n = idx / K, k = idx - n * K;
  float v = (n < N) ? W[(size_t)k * N + n] : 0.f;
  u16 h, l;
  split2(v, h, l);
  Bt[idx] = h;
  Bt[tot + idx] = l;
}

__global__ void add_bias(const float* __restrict__ a, const float* __restrict__ b,
                         float* __restrict__ o, int n) {
  int i = blockIdx.x * blockDim.x + threadIdx.x;
  if (i < n) o[i] = a[i] + b[i];
}

// ---------------- GCN feature-space aggregation (wave per node) ----------------
__global__ void agg_gcn(const u16* __restrict__ xin, const float* __restrict__ dinv,
                        const int* __restrict__ c_off, const int* __restrict__ c_cnt,
                        const int* __restrict__ c_sorted,
                        u16* __restrict__ xout, int n) {
  int wave = (blockIdx.x * blockDim.x + threadIdx.x) >> 6;
  int lane = threadIdx.x & 63;
  if (wave >= n) return;
  int d = wave;
  int start = c_off[d], cnt = c_cnt[d];
  float acc[8] = {};
  const uint4* base = (const uint4*)xin;  // row stride = 64 uint4 (1KB)
  for (int j0 = 0; j0 < cnt; j0 += 64) {
    int nn = cnt - j0; nn = nn < 64 ? nn : 64;
    int sl = (j0 + lane < cnt) ? c_sorted[start + j0 + lane] : 0;
    int jj = 0;
    for (; jj + 4 <= nn; jj += 4) {
      int s0 = __shfl(sl, jj), s1 = __shfl(sl, jj + 1);
      int s2 = __shfl(sl, jj + 2), s3 = __shfl(sl, jj + 3);
      float d0 = dinv[s0], d1 = dinv[s1], d2 = dinv[s2], d3 = dinv[s3];
      uint4 v0 = base[(size_t)s0 * 64 + lane];
      uint4 v1 = base[(size_t)s1 * 64 + lane];
      uint4 v2 = base[(size_t)s2 * 64 + lane];
      uint4 v3 = base[(size_t)s3 * 64 + lane];
      const u16* p0 = (const u16*)&v0;
      const u16* p1 = (const u16*)&v1;
      const u16* p2 = (const u16*)&v2;
      const u16* p3 = (const u16*)&v3;
#pragma unroll
      for (int e = 0; e < 8; ++e) {
        acc[e] = fmaf(bf16f(p0[e]), d0, acc[e]);
        acc[e] = fmaf(bf16f(p1[e]), d1, acc[e]);
        acc[e] = fmaf(bf16f(p2[e]), d2, acc[e]);
        acc[e] = fmaf(bf16f(p3[e]), d3, acc[e]);
      }
    }
    for (; jj < nn; ++jj) {
      int s = __shfl(sl, jj);
      float ds = dinv[s];
      uint4 v = base[(size_t)s * 64 + lane];
      const u16* pv = (const u16*)&v;
#pragma unroll
      for (int e = 0; e < 8; ++e) acc[e] = fmaf(bf16f(pv[e]), ds, acc[e]);
    }
  }
  float dd = dinv[d];
  {
    uint4 v = base[(size_t)d * 64 + lane];
    const u16* pv = (const u16*)&v;
#pragma unroll
    for (int e = 0; e < 8; ++e) acc[e] = fmaf(bf16f(pv[e]), dd, acc[e]);
  }
  union { u16 u[8]; uint4 v; } O;
#pragma unroll
  for (int e = 0; e < 8; ++e) {
    float full = (acc[e] + __shfl_xor(acc[e], 32)) * dd;
    u16 h = bf16_rn(full);
    O.u[e] = (lane < 32) ? h : bf16_rn(full - bf16f(h));
  }
  ((uint4*)xout)[(size_t)d * 64 + lane] = O.v;
}

// ---------------- tri-segment split-bf16 MFMA GEMM ----------------
// C tile 128x64, 4 waves (2x2). A via gload_lds dbuf (32KB LDS).
// B fragments register-double-buffered: step tt+1's B issued at top of step tt,
// drained by the end-of-step barrier (no mid-step vmcnt drain).
template <int NSEG, bool F32OUT, int GY>
__global__ __launch_bounds__(256, 4) void gemm_mfma(
    const u16* __restrict__ A0, const u16* __restrict__ A1, const u16* __restrict__ A2,
    const u16* __restrict__ B0, const u16* __restrict__ B1, const u16* __restrict__ B2,
    int bs0, int bs1, int bs2,
    const float* __restrict__ bias,
    u16* __restrict__ Cp, float* __restrict__ Cf,
    int M, int N) {
  __shared__ u16 Ah[2][4096], Al[2][4096];

  const int t = threadIdx.x;
  const int wid = t >> 6, lane = t & 63;
  const int wr = wid >> 1, wc = wid & 1;
  const int lrow = lane & 15, kslot = lane >> 4;
  const int jsw = kslot ^ ((lrow >> 1) & 3);

  // bijective XCD-chunked block swizzle (m204), column-tile-fastest
  const int nb = gridDim.x;
  const int q = nb >> 3, r = nb & 7;
  const int xcd = blockIdx.x & 7, pos = blockIdx.x >> 3;
  const int lin = (xcd < r ? xcd * (q + 1) : r * (q + 1) + (xcd - r) * q) + pos;
  const int bx = lin / GY, by = lin - bx * GY;
  const int gm = bx * 128;
  const int gn = by * 64;

  const int s_r = lane >> 2;
  const int s_j = (lane & 3) ^ ((s_r >> 1) & 3);

  f32x4 acc[4][2];
  const f32x4 z4 = {0.f, 0.f, 0.f, 0.f};
#pragma unroll
  for (int m = 0; m < 4; ++m) { acc[m][0] = z4; acc[m][1] = z4; }

  const int NT = (NSEG == 3) ? 20 : 8;

  auto STAGE = [&](int tt, int half) {
    const int seg = tt >> 3;
    const int k0 = (tt & 7) * 32;
    const u16* A;
    int rs;
    if (NSEG == 1 || seg == 0) { A = A0; rs = 512; }
    else if (seg == 1)         { A = A1; rs = 512; }
    else                       { A = A2; rs = 256; }
    const int hoff = rs >> 1;
    const int c = wid * 2;
#pragma unroll
    for (int cc = 0; cc < 2; ++cc) {
      int grow = gm + (c + cc) * 16 + s_r;
      grow = grow < M ? grow : M - 1;
      size_t go = (size_t)grow * rs + (k0 + s_j * 8);
      gload16(A + go, &Ah[half][(c + cc) * 512]);
      gload16(A + go + hoff, &Al[half][(c + cc) * 512]);
    }
  };

  auto LOADB = [&](int tt, bf16x8* o) {
    const int seg = tt >> 3;
    const int k0 = (tt & 7) * 32;
    const u16* B;
    int K, bs;
    if (NSEG == 1 || seg == 0) { B = B0; K = 256; bs = bs0; }
    else if (seg == 1)         { B = B1; K = 256; bs = bs1; }
    else                       { B = B2; K = 128; bs = bs2; }
    size_t bo = (size_t)(gn + wc * 32 + lrow) * K + (k0 + kslot * 8);
    o[0] = *(const bf16x8*)(B + bo);
    o[1] = *(const bf16x8*)(B + bo + (size_t)16 * K);
    o[2] = *(const bf16x8*)(B + bs + bo);
    o[3] = *(const bf16x8*)(B + bs + bo + (size_t)16 * K);
  };

  bf16x8 Bcur[4], Bnxt[4];
  LOADB(0, Bcur);
  STAGE(0, 0);
  __syncthreads();  // drains vmcnt(0): buf0 + Bcur ready

  for (int tt = 0; tt < NT; ++tt) {
    const int half = tt & 1;
    if (tt + 1 < NT) {
      LOADB(tt + 1, Bnxt);       // prefetch next B (drains at end-of-step barrier)
      STAGE(tt + 1, half ^ 1);   // prefetch next A tile into other LDS half
    }

    bf16x8 ah[4], al[4];
    const int ab = (wr * 64 + lrow) * 32 + jsw * 8;
#pragma unroll
    for (int m = 0; m < 4; ++m) {
      ah[m] = *(const bf16x8*)&Ah[half][ab + m * 512];
      al[m] = *(const bf16x8*)&Al[half][ab + m * 512];
    }
#pragma unroll
    for (int m = 0; m < 4; ++m) {
      acc[m][0] = __builtin_amdgcn_mfma_f32_16x16x32_bf16(ah[m], Bcur[0], acc[m][0], 0, 0, 0);
      acc[m][0] = __builtin_amdgcn_mfma_f32_16x16x32_bf16(al[m], Bcur[0], acc[m][0], 0, 0, 0);
      acc[m][0] = __builtin_amdgcn_mfma_f32_16x16x32_bf16(ah[m], Bcur[2], acc[m][0], 0, 0, 0);
      acc[m][1] = __builtin_amdgcn_mfma_f32_16x16x32_bf16(ah[m], Bcur[1], acc[m][1], 0, 0, 0);
      acc[m][1] = __builtin_amdgcn_mfma_f32_16x16x32_bf16(al[m], Bcur[1], acc[m][1], 0, 0, 0);
      acc[m][1] = __builtin_amdgcn_mfma_f32_16x16x32_bf16(ah[m], Bcur[3], acc[m][1], 0, 0, 0);
    }
    __syncthreads();  // drains vmcnt(0): next LDS half + Bnxt complete
#pragma unroll
    for (int i = 0; i < 4; ++i) Bcur[i] = Bnxt[i];
  }

  // ---- epilogue ----
  const int col0 = gn + wc * 32 + lrow;
  const int row00 = gm + wr * 64 + kslot * 4;
#pragma unroll
  for (int m = 0; m < 4; ++m) {
#pragma unroll
    for (int i = 0; i < 4; ++i) {
      int row = row00 + m * 16 + i;
      if (row >= M) continue;
#pragma unroll
      for (int n = 0; n < 2; ++n) {
        int col = col0 + n * 16;
        float bv = (col < N) ? bias[col] : 0.f;
        float v = acc[m][n][i] + bv;
        if (F32OUT) {
          if (col < N) Cf[(size_t)row * N + col] = v;
        } else {
          v = fmaxf(v, 0.f);
          u16 h, l;
          split2(v, h, l);
          Cp[(size_t)row * 512 + col] = h;
          Cp[(size_t)row * 512 + 256 + col] = l;
        }
      }
    }
  }
}

// ---------------- launch ----------------
static inline size_t align_up(size_t x) { return (x + 255) & ~(size_t)255; }

extern "C" void kernel_launch(void* const* d_in, const int* in_sizes, int n_in,
                              void* d_out, int out_size, void* d_ws, size_t ws_size,
                              hipStream_t stream) {
  const float* x_paper  = (const float*)d_in[0];
  const float* x_author = (const float*)d_in[1];
  const int*   cites    = (const int*)d_in[2];
  const int*   w_src    = (const int*)d_in[3];
  const int*   w_dst    = (const int*)d_in[4];
  const float* W1  = (const float*)d_in[5];
  const float* b1  = (const float*)d_in[6];
  const float* Wl1 = (const float*)d_in[7];
  const float* bl1 = (const float*)d_in[8];
  const float* Wr1 = (const float*)d_in[9];
  const float* W2  = (const float*)d_in[10];
  const float* b2  = (const float*)d_in[11];
  const float* Wl2 = (const float*)d_in[12];
  const float* bl2 = (const float*)d_in[13];
  const float* Wr2 = (const float*)d_in[14];
  const float* linW = (const float*)d_in[15];
  const float* linb = (const float*)d_in[16];
  float* out = (float*)d_out;

  const int N = in_sizes[0] / DP;  // 100000
  const int E = in_sizes[3];       // 1000000
  const int* c_src = cites;
  const int* c_dst = cites + E;

  char* w = (char*)d_ws;
  size_t off = 0;
  auto alloc = [&](size_t bytes) -> void* {
    void* p = w + off;
    off = align_up(off + bytes);
    return p;
  };
  int* deg_c      = (int*)alloc((size_t)N * 4);
  int* cnt_w      = (int*)alloc((size_t)N * 4);
  int* cites_off  = (int*)alloc((size_t)N * 4);
  int* writes_off = (int*)alloc((size_t)N * 4);
  int* cur_c      = (int*)alloc((size_t)N * 4);
  int* cur_w      = (int*)alloc((size_t)N * 4);
  int* bsumA      = (int*)alloc(256 * 4);
  int* bsumB      = (int*)alloc(256 * 4);
  int* c_sorted   = (int*)alloc((size_t)E * 4);
  int* w_sorted   = (int*)alloc((size_t)E * 4);
  float* dinv     = (float*)alloc((size_t)N * 4);
  u16* meanA      = (u16*)alloc((size_t)N * 256 * 2);   // paired [N][256]
  u16* xp         = (u16*)alloc((size_t)N * 512 * 2);   // paired [N][512]
  u16* xs         = (u16*)alloc((size_t)N * 512 * 2);
  u16* pb         = (u16*)alloc((size_t)N * 512 * 2);
  const int bsW = 256 * 256, bsL = 256 * 128, bsLin = 384 * 256;
  u16* BtW1  = (u16*)alloc((size_t)2 * bsW * 2);
  u16* BtWr1 = (u16*)alloc((size_t)2 * bsW * 2);
  u16* BtW2  = (u16*)alloc((size_t)2 * bsW * 2);
  u16* BtWr2 = (u16*)alloc((size_t)2 * bsW * 2);
  u16* BtWl1 = (u16*)alloc((size_t)2 * bsL * 2);
  u16* BtWl2 = (u16*)alloc((size_t)2 * bsL * 2);
  u16* BtLin = (u16*)alloc((size_t)2 * bsLin * 2);
  float* biasR1 = (float*)alloc(HIDN * 4);
  float* biasR2 = (float*)alloc(HIDN * 4);
  (void)ws_size; (void)n_in; (void)out_size;

  hipMemsetAsync(deg_c, 0, (size_t)N * 4, stream);
  hipMemsetAsync(cnt_w, 0, (size_t)N * 4, stream);

  int nbE = (E + 255) / 256;
  hist_kernel<<<nbE, 256, 0, stream>>>(c_dst, w_dst, deg_c, cnt_w, E);

  int nsb = (N + SCAN_TILE - 1) / SCAN_TILE;
  scan_local<<<nsb, SCAN_TPB, 0, stream>>>(deg_c, cites_off, bsumA, N);
  scan_spine<<<1, 256, 0, stream>>>(bsumA, nsb);
  scan_add<<<nsb, SCAN_TPB, 0, stream>>>(cites_off, bsumA, N);
  scan_local<<<nsb, SCAN_TPB, 0, stream>>>(cnt_w, writes_off, bsumB, N);
  scan_spine<<<1, 256, 0, stream>>>(bsumB, nsb);
  scan_add<<<nsb, SCAN_TPB, 0, stream>>>(writes_off, bsumB, N);

  hipMemcpyAsync(cur_c, cites_off, (size_t)N * 4, hipMemcpyDeviceToDevice, stream);
  hipMemcpyAsync(cur_w, writes_off, (size_t)N * 4, hipMemcpyDeviceToDevice, stream);
  fill_csr<<<nbE, 256, 0, stream>>>(c_src, c_dst, w_src, w_dst, cur_c, cur_w,
                                    c_sorted, w_sorted, E);

  // conversions (independent of CSR)
  int n8 = N * 32;
  conv_split<<<(n8 + 255) / 256, 256, 0, stream>>>(x_paper, xp, n8);
  prep_weight<<<(bsW + 255) / 256, 256, 0, stream>>>(W1, 256, 256, 256, BtW1);
  prep_weight<<<(bsW + 255) / 256, 256, 0, stream>>>(Wr1, 256, 256, 256, BtWr1);
  prep_weight<<<(bsW + 255) / 256, 256, 0, stream>>>(W2, 256, 256, 256, BtW2);
  prep_weight<<<(bsW + 255) / 256, 256, 0, stream>>>(Wr2, 256, 256, 256, BtWr2);
  prep_weight<<<(bsL + 255) / 256, 256, 0, stream>>>(Wl1, 128, 256, 256, BtWl1);
  prep_weight<<<(bsL + 255) / 256, 256, 0, stream>>>(Wl2, 128, 256, 256, BtWl2);
  prep_weight<<<(bsLin + 255) / 256, 256, 0, stream>>>(linW, 256, DOUT, 384, BtLin);
  add_bias<<<1, 256, 0, stream>>>(b1, bl1, biasR1, HIDN);
  add_bias<<<1, 256, 0, stream>>>(b2, bl2, biasR2, HIDN);

  int nbWave = (N * 64 + 255) / 256;
  node_prep<<<nbWave, 256, 0, stream>>>(x_author, writes_off, cnt_w, w_sorted,
                                        deg_c, meanA, dinv, N);

  const int GX = (N + 127) / 128;  // 782

  // layer 1
  agg_gcn<<<nbWave, 256, 0, stream>>>(xp, dinv, cites_off, deg_c, c_sorted, xs, N);
  gemm_mfma<3, false, 4><<<GX * 4, 256, 0, stream>>>(
      xs, xp, meanA, BtW1, BtWr1, BtWl1, bsW, bsW, bsL,
      biasR1, pb, nullptr, N, HIDN);
  // layer 2
  agg_gcn<<<nbWave, 256, 0, stream>>>(pb, dinv, cites_off, deg_c, c_sorted, xs, N);
  gemm_mfma<3, false, 4><<<GX * 4, 256, 0, stream>>>(
      xs, pb, meanA, BtW2, BtWr2, BtWl2, bsW, bsW, bsL,
      biasR2, xp, nullptr, N, HIDN);
  // output projection
  gemm_mfma<1, true, 6><<<GX * 6, 256, 0, stream>>>(
      xp, nullptr, nullptr, BtLin, nullptr, nullptr, bsLin, 0, 0,
      linb, nullptr, out, N, DOUT);
}

// Round 6
// 724.676 us; speedup vs baseline: 1.7876x; 1.7821x over previous
//
#include <hip/hip_runtime.h>

// HeteroGNN on MI355X — round 6: plain-bf16 pipeline (f32 accumulate).
//   - features/weights single-plane bf16 (absmax evidence: compare path is bf16)
//   - GEMM tile 128x256 (ALL cols per block) -> A read once; B via LDS; 8 waves
//   - agg_gcn gathers 512B bf16 rows; x_author pre-converted to bf16

#define DP   256
#define DA   128
#define HIDN 256
#define DOUT 349

typedef unsigned short u16;
typedef __attribute__((ext_vector_type(8))) short bf16x8;
typedef __attribute__((ext_vector_type(4))) float f32x4;

__device__ __forceinline__ u16 bf16_rn(float x) {
  union { float f; unsigned u; } v; v.f = x;
  unsigned r = v.u + 0x7FFFu + ((v.u >> 16) & 1u);
  return (u16)(r >> 16);
}
__device__ __forceinline__ float bf16f(u16 h) {
  union { float f; unsigned u; } v; v.u = ((unsigned)h) << 16; return v.f;
}
__device__ __forceinline__ unsigned pack2(float a, float b) {
  return (unsigned)bf16_rn(a) | ((unsigned)bf16_rn(b) << 16);
}

__device__ __forceinline__ void gload16(const void* g, void* lds) {
  __builtin_amdgcn_global_load_lds(
      (const __attribute__((address_space(1))) unsigned int*)g,
      (__attribute__((address_space(3))) unsigned int*)lds, 16, 0, 0);
}

// ---------------- histogram ----------------
__global__ void hist_kernel(const int* __restrict__ c_dst, const int* __restrict__ w_dst,
                            int* __restrict__ deg_c, int* __restrict__ cnt_w, int e) {
  int i = blockIdx.x * blockDim.x + threadIdx.x;
  if (i < e) {
    atomicAdd(&deg_c[c_dst[i]], 1);
    atomicAdd(&cnt_w[w_dst[i]], 1);
  }
}

// ---------------- exclusive scan ----------------
#define SCAN_TPB 256
#define SCAN_VPT 8
#define SCAN_TILE 2048

__global__ void scan_local(const int* __restrict__ in, int* __restrict__ out,
                           int* __restrict__ bsum, int n) {
  __shared__ int sdata[SCAN_TPB];
  int t = threadIdx.x;
  int base = blockIdx.x * SCAN_TILE + t * SCAN_VPT;
  int v[SCAN_VPT];
  int sum = 0;
#pragma unroll
  for (int j = 0; j < SCAN_VPT; ++j) {
    int idx = base + j;
    v[j] = (idx < n) ? in[idx] : 0;
    sum += v[j];
  }
  sdata[t] = sum;
  __syncthreads();
  for (int off = 1; off < SCAN_TPB; off <<= 1) {
    int x = (t >= off) ? sdata[t - off] : 0;
    __syncthreads();
    sdata[t] += x;
    __syncthreads();
  }
  int prefix = sdata[t] - sum;
  if (t == SCAN_TPB - 1) bsum[blockIdx.x] = sdata[t];
  int run = prefix;
#pragma unroll
  for (int j = 0; j < SCAN_VPT; ++j) {
    int idx = base + j;
    if (idx < n) out[idx] = run;
    run += v[j];
  }
}

__global__ void scan_spine(int* __restrict__ bsum, int nb) {
  __shared__ int sdata[256];
  int t = threadIdx.x;
  int v = (t < nb) ? bsum[t] : 0;
  sdata[t] = v;
  __syncthreads();
  for (int off = 1; off < 256; off <<= 1) {
    int x = (t >= off) ? sdata[t - off] : 0;
    __syncthreads();
    sdata[t] += x;
    __syncthreads();
  }
  if (t < nb) bsum[t] = sdata[t] - v;
}

__global__ void scan_add(int* __restrict__ out, const int* __restrict__ bsum, int n) {
  int add = bsum[blockIdx.x];
  int base = blockIdx.x * SCAN_TILE + threadIdx.x * SCAN_VPT;
#pragma unroll
  for (int j = 0; j < SCAN_VPT; ++j) {
    int idx = base + j;
    if (idx < n) out[idx] += add;
  }
}

// ---------------- CSR fill ----------------
__global__ void fill_csr(const int* __restrict__ c_src, const int* __restrict__ c_dst,
                         const int* __restrict__ w_src, const int* __restrict__ w_dst,
                         int* __restrict__ cur_c, int* __restrict__ cur_w,
                         int* __restrict__ c_sorted, int* __restrict__ w_sorted, int e) {
  int i = blockIdx.x * blockDim.x + threadIdx.x;
  if (i < e) {
    int d = c_dst[i];
    int pos = atomicAdd(&cur_c[d], 1);
    c_sorted[pos] = c_src[i];
    int d2 = w_dst[i];
    int pos2 = atomicAdd(&cur_w[d2], 1);
    w_sorted[pos2] = w_src[i];
  }
}

// ---------------- f32 -> bf16 convert ----------------
__global__ void conv_bf16(const float* __restrict__ x, u16* __restrict__ o, int n8) {
  int i = blockIdx.x * blockDim.x + threadIdx.x;
  if (i >= n8) return;
  const float4* x4 = (const float4*)x;
  float4 v0 = x4[(size_t)i * 2];
  float4 v1 = x4[(size_t)i * 2 + 1];
  uint4 O;
  O.x = pack2(v0.x, v0.y);
  O.y = pack2(v0.z, v0.w);
  O.z = pack2(v1.x, v1.y);
  O.w = pack2(v1.z, v1.w);
  ((uint4*)o)[i] = O;
}

// ---------------- weight prep: W[K][N] -> Bt[Npad][K] bf16 ----------------
__global__ void prep_weight(const float* __restrict__ W, int K, int N, int Npad,
                            u16* __restrict__ Bt) {
  int idx = blockIdx.x * blockDim.x + threadIdx.x;
  int tot = Npad * K;
  if (idx >= tot) return;
  int n = idx / K, k = idx - n * K;
  float v = (n < N) ? W[(size_t)k * N + n] : 0.f;
  Bt[idx] = bf16_rn(v);
}

__global__ void pad_bias(const float* __restrict__ a, const float* __restrict__ b,
                         float* __restrict__ o, int n, int npad) {
  int i = blockIdx.x * blockDim.x + threadIdx.x;
  if (i < npad) o[i] = (i < n) ? (a[i] + (b ? b[i] : 0.f)) : 0.f;
}

// ---------------- node prep: dinv + author-mean (bf16 gather) ----------------
__global__ void node_prep(const u16* __restrict__ xa16,
                          const int* __restrict__ w_off, const int* __restrict__ w_cnt,
                          const int* __restrict__ w_sorted,
                          const int* __restrict__ deg_c,
                          u16* __restrict__ mean, float* __restrict__ dinv, int n) {
  int wave = (blockIdx.x * blockDim.x + threadIdx.x) >> 6;
  int lane = threadIdx.x & 63;
  if (wave >= n) return;
  int d = wave;
  int start = w_off[d];
  int cnt = w_cnt[d];
  float ax = 0.f, ay = 0.f;
  const unsigned* xa = (const unsigned*)xa16;  // row = 64 uints
  for (int j0 = 0; j0 < cnt; j0 += 64) {
    int nn = cnt - j0; nn = nn < 64 ? nn : 64;
    int sl = (j0 + lane < cnt) ? w_sorted[start + j0 + lane] : 0;
    int jj = 0;
    for (; jj + 4 <= nn; jj += 4) {
      int s0 = __shfl(sl, jj), s1 = __shfl(sl, jj + 1);
      int s2 = __shfl(sl, jj + 2), s3 = __shfl(sl, jj + 3);
      unsigned v0 = xa[(size_t)s0 * 64 + lane];
      unsigned v1 = xa[(size_t)s1 * 64 + lane];
      unsigned v2 = xa[(size_t)s2 * 64 + lane];
      unsigned v3 = xa[(size_t)s3 * 64 + lane];
      ax += bf16f((u16)v0) + bf16f((u16)v1) + bf16f((u16)v2) + bf16f((u16)v3);
      ay += bf16f((u16)(v0 >> 16)) + bf16f((u16)(v1 >> 16)) +
            bf16f((u16)(v2 >> 16)) + bf16f((u16)(v3 >> 16));
    }
    for (; jj < nn; ++jj) {
      int s = __shfl(sl, jj);
      unsigned v = xa[(size_t)s * 64 + lane];
      ax += bf16f((u16)v);
      ay += bf16f((u16)(v >> 16));
    }
  }
  float inv = 1.0f / (float)((cnt > 0) ? cnt : 1);
  ((unsigned*)mean)[(size_t)d * 64 + lane] = pack2(ax * inv, ay * inv);
  if (lane == 0) dinv[d] = rsqrtf((float)(deg_c[d] + 1));
}

// ---------------- GCN feature-space aggregation (wave per node, bf16 rows) ----
// xout[d] = bf16( dinv[d]*( sum_nbr dinv[s]*x[s] + dinv[d]*x[d] ) )
__global__ void agg_gcn(const u16* __restrict__ xin, const float* __restrict__ dinv,
                        const int* __restrict__ c_off, const int* __restrict__ c_cnt,
                        const int* __restrict__ c_sorted,
                        u16* __restrict__ xout, int n) {
  int wave = (blockIdx.x * blockDim.x + threadIdx.x) >> 6;
  int lane = threadIdx.x & 63;
  if (wave >= n) return;
  int d = wave;
  int start = c_off[d], cnt = c_cnt[d];
  float a0 = 0.f, a1 = 0.f, a2 = 0.f, a3 = 0.f;
  const uint2* base = (const uint2*)xin;  // row = 64 uint2 (512B)
  for (int j0 = 0; j0 < cnt; j0 += 64) {
    int nn = cnt - j0; nn = nn < 64 ? nn : 64;
    int sl = (j0 + lane < cnt) ? c_sorted[start + j0 + lane] : 0;
    int jj = 0;
    for (; jj + 4 <= nn; jj += 4) {
      int s0 = __shfl(sl, jj), s1 = __shfl(sl, jj + 1);
      int s2 = __shfl(sl, jj + 2), s3 = __shfl(sl, jj + 3);
      float d0 = dinv[s0], d1 = dinv[s1], d2 = dinv[s2], d3 = dinv[s3];
      uint2 v0 = base[(size_t)s0 * 64 + lane];
      uint2 v1 = base[(size_t)s1 * 64 + lane];
      uint2 v2 = base[(size_t)s2 * 64 + lane];
      uint2 v3 = base[(size_t)s3 * 64 + lane];
      a0 = fmaf(bf16f((u16)v0.x), d0, a0); a1 = fmaf(bf16f((u16)(v0.x >> 16)), d0, a1);
      a2 = fmaf(bf16f((u16)v0.y), d0, a2); a3 = fmaf(bf16f((u16)(v0.y >> 16)), d0, a3);
      a0 = fmaf(bf16f((u16)v1.x), d1, a0); a1 = fmaf(bf16f((u16)(v1.x >> 16)), d1, a1);
      a2 = fmaf(bf16f((u16)v1.y), d1, a2); a3 = fmaf(bf16f((u16)(v1.y >> 16)), d1, a3);
      a0 = fmaf(bf16f((u16)v2.x), d2, a0); a1 = fmaf(bf16f((u16)(v2.x >> 16)), d2, a1);
      a2 = fmaf(bf16f((u16)v2.y), d2, a2); a3 = fmaf(bf16f((u16)(v2.y >> 16)), d2, a3);
      a0 = fmaf(bf16f((u16)v3.x), d3, a0); a1 = fmaf(bf16f((u16)(v3.x >> 16)), d3, a1);
      a2 = fmaf(bf16f((u16)v3.y), d3, a2); a3 = fmaf(bf16f((u16)(v3.y >> 16)), d3, a3);
    }
    for (; jj < nn; ++jj) {
      int s = __shfl(sl, jj);
      float ds = dinv[s];
      uint2 v = base[(size_t)s * 64 + lane];
      a0 = fmaf(bf16f((u16)v.x), ds, a0); a1 = fmaf(bf16f((u16)(v.x >> 16)), ds, a1);
      a2 = fmaf(bf16f((u16)v.y), ds, a2); a3 = fmaf(bf16f((u16)(v.y >> 16)), ds, a3);
    }
  }
  float dd = dinv[d];
  {
    uint2 v = base[(size_t)d * 64 + lane];
    a0 = fmaf(bf16f((u16)v.x), dd, a0); a1 = fmaf(bf16f((u16)(v.x >> 16)), dd, a1);
    a2 = fmaf(bf16f((u16)v.y), dd, a2); a3 = fmaf(bf16f((u16)(v.y >> 16)), dd, a3);
  }
  uint2 O;
  O.x = pack2(a0 * dd, a1 * dd);
  O.y = pack2(a2 * dd, a3 * dd);
  ((uint2*)xout)[(size_t)d * 64 + lane] = O;
}

// ---------------- bf16 MFMA GEMM: tile 128 x 256, 8 waves (2x4) ----------------
// NSEG=3: C = A0@B0 + A1@B1 + A2@B2(K=128) + bias -> relu -> bf16 [M][256]
// NSEG=1: C = A0@B0 + bias -> f32 [M][N] (col-masked), NC col tiles of 256
template <int NSEG, bool F32OUT, int NC>
__global__ __launch_bounds__(512, 4) void gemm_bf16(
    const u16* __restrict__ A0, const u16* __restrict__ A1, const u16* __restrict__ A2,
    const u16* __restrict__ B0, const u16* __restrict__ B1, const u16* __restrict__ B2,
    const float* __restrict__ bias,
    u16* __restrict__ Cp, float* __restrict__ Cf,
    int M, int N) {
  __shared__ u16 Ah[2][4096];   // 128 rows x 32 k
  __shared__ u16 Bh[2][8192];   // 256 cols x 32 k

  const int t = threadIdx.x;
  const int wid = t >> 6, lane = t & 63;
  const int wr = wid >> 2, wc = wid & 3;
  const int lrow = lane & 15, kslot = lane >> 4;
  const int jsw = kslot ^ ((lrow >> 1) & 3);

  // bijective XCD-chunked block swizzle (m204), col-fastest
  const int nb = gridDim.x;
  const int q = nb >> 3, r = nb & 7;
  const int xcd = blockIdx.x & 7, pos = blockIdx.x >> 3;
  const int lin = (xcd < r ? xcd * (q + 1) : r * (q + 1) + (xcd - r) * q) + pos;
  const int bx = lin / NC, by = lin - bx * NC;
  const int gm = bx * 128;
  const int gn = by * 256;

  const int s_r = lane >> 2;
  const int s_j = (lane & 3) ^ ((s_r >> 1) & 3);

  f32x4 acc[4][4];
  const f32x4 z4 = {0.f, 0.f, 0.f, 0.f};
#pragma unroll
  for (int m = 0; m < 4; ++m)
#pragma unroll
    for (int n = 0; n < 4; ++n) acc[m][n] = z4;

  const int NT = (NSEG == 3) ? 20 : 8;

  auto STAGE = [&](int tt, int half) {
    const u16* A;
    const u16* B;
    int rs, k0;
    if (NSEG == 3 && tt >= 16)     { A = A2; B = B2; rs = 128; k0 = (tt - 16) * 32; }
    else if (NSEG == 3 && tt >= 8) { A = A1; B = B1; rs = 256; k0 = (tt - 8) * 32; }
    else                           { A = A0; B = B0; rs = 256; k0 = tt * 32; }
    {
      int grow = gm + wid * 16 + s_r;
      grow = grow < M ? grow : M - 1;
      gload16(A + (size_t)grow * rs + (k0 + s_j * 8), &Ah[half][wid * 512]);
    }
#pragma unroll
    for (int c = 0; c < 2; ++c) {
      int chunk = wid * 2 + c;
      int col = gn + chunk * 16 + s_r;
      gload16(B + (size_t)col * rs + (k0 + s_j * 8), &Bh[half][chunk * 512]);
    }
  };

  STAGE(0, 0);
  __syncthreads();

  for (int tt = 0; tt < NT; ++tt) {
    const int half = tt & 1;
    if (tt + 1 < NT) STAGE(tt + 1, half ^ 1);

    bf16x8 ah[4];
    const int ab = (wr * 64 + lrow) * 32 + jsw * 8;
#pragma unroll
    for (int m = 0; m < 4; ++m) ah[m] = *(const bf16x8*)&Ah[half][ab + m * 512];
    const int bb = (wc * 64 + lrow) * 32 + jsw * 8;
#pragma unroll
    for (int n = 0; n < 4; ++n) {
      bf16x8 bn = *(const bf16x8*)&Bh[half][bb + n * 512];
#pragma unroll
      for (int m = 0; m < 4; ++m)
        acc[m][n] = __builtin_amdgcn_mfma_f32_16x16x32_bf16(ah[m], bn, acc[m][n], 0, 0, 0);
    }
    __syncthreads();
  }

  // ---- epilogue ----
  const int col0 = gn + wc * 64 + lrow;
  const int row00 = gm + wr * 64 + kslot * 4;
#pragma unroll
  for (int m = 0; m < 4; ++m) {
#pragma unroll
    for (int i = 0; i < 4; ++i) {
      int row = row00 + m * 16 + i;
      if (row >= M) continue;
#pragma unroll
      for (int n = 0; n < 4; ++n) {
        int col = col0 + n * 16;
        float v = acc[m][n][i] + bias[col];
        if (F32OUT) {
          if (col < N) Cf[(size_t)row * N + col] = v;
        } else {
          Cp[(size_t)row * 256 + col] = bf16_rn(fmaxf(v, 0.f));
        }
      }
    }
  }
}

// ---------------- launch ----------------
static inline size_t align_up(size_t x) { return (x + 255) & ~(size_t)255; }

extern "C" void kernel_launch(void* const* d_in, const int* in_sizes, int n_in,
                              void* d_out, int out_size, void* d_ws, size_t ws_size,
                              hipStream_t stream) {
  const float* x_paper  = (const float*)d_in[0];
  const float* x_author = (const float*)d_in[1];
  const int*   cites    = (const int*)d_in[2];
  const int*   w_src    = (const int*)d_in[3];
  const int*   w_dst    = (const int*)d_in[4];
  const float* W1  = (const float*)d_in[5];
  const float* b1  = (const float*)d_in[6];
  const float* Wl1 = (const float*)d_in[7];
  const float* bl1 = (const float*)d_in[8];
  const float* Wr1 = (const float*)d_in[9];
  const float* W2  = (const float*)d_in[10];
  const float* b2  = (const float*)d_in[11];
  const float* Wl2 = (const float*)d_in[12];
  const float* bl2 = (const float*)d_in[13];
  const float* Wr2 = (const float*)d_in[14];
  const float* linW = (const float*)d_in[15];
  const float* linb = (const float*)d_in[16];
  float* out = (float*)d_out;

  const int N = in_sizes[0] / DP;       // 100000
  const int NA = in_sizes[1] / DA;      // 50000
  const int E = in_sizes[3];            // 1000000
  const int* c_src = cites;
  const int* c_dst = cites + E;

  char* w = (char*)d_ws;
  size_t off = 0;
  auto alloc = [&](size_t bytes) -> void* {
    void* p = w + off;
    off = align_up(off + bytes);
    return p;
  };
  int* deg_c      = (int*)alloc((size_t)N * 4);
  int* cnt_w      = (int*)alloc((size_t)N * 4);
  int* cites_off  = (int*)alloc((size_t)N * 4);
  int* writes_off = (int*)alloc((size_t)N * 4);
  int* cur_c      = (int*)alloc((size_t)N * 4);
  int* cur_w      = (int*)alloc((size_t)N * 4);
  int* bsumA      = (int*)alloc(256 * 4);
  int* bsumB      = (int*)alloc(256 * 4);
  int* c_sorted   = (int*)alloc((size_t)E * 4);
  int* w_sorted   = (int*)alloc((size_t)E * 4);
  float* dinv     = (float*)alloc((size_t)N * 4);
  u16* xa16       = (u16*)alloc((size_t)NA * DA * 2);
  u16* meanA      = (u16*)alloc((size_t)N * DA * 2);
  u16* xp         = (u16*)alloc((size_t)N * 256 * 2);
  u16* xs         = (u16*)alloc((size_t)N * 256 * 2);
  u16* pb         = (u16*)alloc((size_t)N * 256 * 2);
  const int bsW = 256 * 256, bsL = 256 * 128, bsLin = 512 * 256;
  u16* BtW1  = (u16*)alloc((size_t)bsW * 2);
  u16* BtWr1 = (u16*)alloc((size_t)bsW * 2);
  u16* BtW2  = (u16*)alloc((size_t)bsW * 2);
  u16* BtWr2 = (u16*)alloc((size_t)bsW * 2);
  u16* BtWl1 = (u16*)alloc((size_t)bsL * 2);
  u16* BtWl2 = (u16*)alloc((size_t)bsL * 2);
  u16* BtLin = (u16*)alloc((size_t)bsLin * 2);
  float* biasR1  = (float*)alloc(256 * 4);
  float* biasR2  = (float*)alloc(256 * 4);
  float* biasLin = (float*)alloc(512 * 4);
  (void)ws_size; (void)n_in; (void)out_size;

  hipMemsetAsync(deg_c, 0, (size_t)N * 4, stream);
  hipMemsetAsync(cnt_w, 0, (size_t)N * 4, stream);

  int nbE = (E + 255) / 256;
  hist_kernel<<<nbE, 256, 0, stream>>>(c_dst, w_dst, deg_c, cnt_w, E);

  int nsb = (N + SCAN_TILE - 1) / SCAN_TILE;
  scan_local<<<nsb, SCAN_TPB, 0, stream>>>(deg_c, cites_off, bsumA, N);
  scan_spine<<<1, 256, 0, stream>>>(bsumA, nsb);
  scan_add<<<nsb, SCAN_TPB, 0, stream>>>(cites_off, bsumA, N);
  scan_local<<<nsb, SCAN_TPB, 0, stream>>>(cnt_w, writes_off, bsumB, N);
  scan_spine<<<1, 256, 0, stream>>>(bsumB, nsb);
  scan_add<<<nsb, SCAN_TPB, 0, stream>>>(writes_off, bsumB, N);

  hipMemcpyAsync(cur_c, cites_off, (size_t)N * 4, hipMemcpyDeviceToDevice, stream);
  hipMemcpyAsync(cur_w, writes_off, (size_t)N * 4, hipMemcpyDeviceToDevice, stream);
  fill_csr<<<nbE, 256, 0, stream>>>(c_src, c_dst, w_src, w_dst, cur_c, cur_w,
                                    c_sorted, w_sorted, E);

  // conversions (independent of CSR)
  conv_bf16<<<(N * 32 + 255) / 256, 256, 0, stream>>>(x_paper, xp, N * 32);
  conv_bf16<<<(NA * 16 + 255) / 256, 256, 0, stream>>>(x_author, xa16, NA * 16);
  prep_weight<<<(bsW + 255) / 256, 256, 0, stream>>>(W1, 256, 256, 256, BtW1);
  prep_weight<<<(bsW + 255) / 256, 256, 0, stream>>>(Wr1, 256, 256, 256, BtWr1);
  prep_weight<<<(bsW + 255) / 256, 256, 0, stream>>>(W2, 256, 256, 256, BtW2);
  prep_weight<<<(bsW + 255) / 256, 256, 0, stream>>>(Wr2, 256, 256, 256, BtWr2);
  prep_weight<<<(bsL + 255) / 256, 256, 0, stream>>>(Wl1, 128, 256, 256, BtWl1);
  prep_weight<<<(bsL + 255) / 256, 256, 0, stream>>>(Wl2, 128, 256, 256, BtWl2);
  prep_weight<<<(bsLin + 255) / 256, 256, 0, stream>>>(linW, 256, DOUT, 512, BtLin);
  pad_bias<<<1, 256, 0, stream>>>(b1, bl1, biasR1, 256, 256);
  pad_bias<<<1, 256, 0, stream>>>(b2, bl2, biasR2, 256, 256);
  pad_bias<<<2, 256, 0, stream>>>(linb, nullptr, biasLin, DOUT, 512);

  int nbWave = (N * 64 + 255) / 256;
  node_prep<<<nbWave, 256, 0, stream>>>(xa16, writes_off, cnt_w, w_sorted,
                                        deg_c, meanA, dinv, N);

  const int GX = (N + 127) / 128;  // 782

  // layer 1
  agg_gcn<<<nbWave, 256, 0, stream>>>(xp, dinv, cites_off, deg_c, c_sorted, xs, N);
  gemm_bf16<3, false, 1><<<GX, 512, 0, stream>>>(
      xs, xp, meanA, BtW1, BtWr1, BtWl1, biasR1, pb, nullptr, N, HIDN);
  // layer 2
  agg_gcn<<<nbWave, 256, 0, stream>>>(pb, dinv, cites_off, deg_c, c_sorted, xs, N);
  gemm_bf16<3, false, 1><<<GX, 512, 0, stream>>>(
      xs, pb, meanA, BtW2, BtWr2, BtWl2, biasR2, xp, nullptr, N, HIDN);
  // output projection (2 col tiles of 256, masked to 349)
  gemm_bf16<1, true, 2><<<GX * 2, 512, 0, stream>>>(
      xp, nullptr, nullptr, BtLin, nullptr, nullptr, biasLin, nullptr, out, N, DOUT);
}

// Round 7
// 542.237 us; speedup vs baseline: 2.3890x; 1.3365x over previous
//
#include <hip/hip_runtime.h>

// HeteroGNN on MI355X — round 7: bf16 pipeline + chunked counting-sort CSR build.
//   fill_csr's 132MB write-amplified scatter replaced by:
//     S1: per-4096-edge-chunk LDS bucket sort (782 buckets of 128 nodes),
//         block-private tmp regions (no cross-XCD line sharing)
//     S2: scan of [bucket][chunk] counts (3-kernel scan)
//     S4: per-bucket exact counting sort in LDS -> coalesced c_sorted + deg + off

#define DP   256
#define DA   128
#define HIDN 256
#define DOUT 349
#define NBKT 782          // ceil(100000/128)
#define CHUNK 4096

typedef unsigned short u16;
typedef unsigned int u32;
typedef __attribute__((ext_vector_type(8))) short bf16x8;
typedef __attribute__((ext_vector_type(4))) float f32x4;

__device__ __forceinline__ u16 bf16_rn(float x) {
  union { float f; unsigned u; } v; v.f = x;
  unsigned r = v.u + 0x7FFFu + ((v.u >> 16) & 1u);
  return (u16)(r >> 16);
}
__device__ __forceinline__ float bf16f(u16 h) {
  union { float f; unsigned u; } v; v.u = ((unsigned)h) << 16; return v.f;
}
__device__ __forceinline__ unsigned pack2(float a, float b) {
  return (unsigned)bf16_rn(a) | ((unsigned)bf16_rn(b) << 16);
}

__device__ __forceinline__ void gload16(const void* g, void* lds) {
  __builtin_amdgcn_global_load_lds(
      (const __attribute__((address_space(1))) unsigned int*)g,
      (__attribute__((address_space(3))) unsigned int*)lds, 16, 0, 0);
}

// ---------------- exclusive scan (2048/block) ----------------
#define SCAN_TPB 256
#define SCAN_VPT 8
#define SCAN_TILE 2048

__global__ void scan_local(const int* __restrict__ in, int* __restrict__ out,
                           int* __restrict__ bsum, int n) {
  __shared__ int sdata[SCAN_TPB];
  int t = threadIdx.x;
  int base = blockIdx.x * SCAN_TILE + t * SCAN_VPT;
  int v[SCAN_VPT];
  int sum = 0;
#pragma unroll
  for (int j = 0; j < SCAN_VPT; ++j) {
    int idx = base + j;
    v[j] = (idx < n) ? in[idx] : 0;
    sum += v[j];
  }
  sdata[t] = sum;
  __syncthreads();
  for (int off = 1; off < SCAN_TPB; off <<= 1) {
    int x = (t >= off) ? sdata[t - off] : 0;
    __syncthreads();
    sdata[t] += x;
    __syncthreads();
  }
  int prefix = sdata[t] - sum;
  if (t == SCAN_TPB - 1) bsum[blockIdx.x] = sdata[t];
  int run = prefix;
#pragma unroll
  for (int j = 0; j < SCAN_VPT; ++j) {
    int idx = base + j;
    if (idx < n) out[idx] = run;
    run += v[j];
  }
}

__global__ void scan_spine(int* __restrict__ bsum, int nb) {
  __shared__ int sdata[256];
  int t = threadIdx.x;
  int v = (t < nb) ? bsum[t] : 0;
  sdata[t] = v;
  __syncthreads();
  for (int off = 1; off < 256; off <<= 1) {
    int x = (t >= off) ? sdata[t - off] : 0;
    __syncthreads();
    sdata[t] += x;
    __syncthreads();
  }
  if (t < nb) bsum[t] = sdata[t] - v;
}

__global__ void scan_add(int* __restrict__ out, const int* __restrict__ bsum, int n) {
  int add = bsum[blockIdx.x];
  int base = blockIdx.x * SCAN_TILE + threadIdx.x * SCAN_VPT;
#pragma unroll
  for (int j = 0; j < SCAN_VPT; ++j) {
    int idx = base + j;
    if (idx < n) out[idx] += add;
  }
}

// ---------------- sort pass 1: chunk -> bucket-grouped tmp ----------------
__global__ __launch_bounds__(256) void sort_pass1(
    const int* __restrict__ src, const int* __restrict__ dst,
    uint2* __restrict__ tmp, int* __restrict__ gcount, int* __restrict__ lofs,
    int E, int nch) {
  const int c = blockIdx.x, t = threadIdx.x;
  __shared__ u32 cnt[NBKT];
  __shared__ u32 ofs[NBKT];
  __shared__ u32 sdata[256];
  __shared__ uint2 stage[CHUNK];

  for (int i = t; i < NBKT; i += 256) cnt[i] = 0;
  __syncthreads();
  const int base = c * CHUNK;
#pragma unroll
  for (int j = 0; j < 16; ++j) {
    int i = t + j * 256, idx = base + i;
    if (idx < E) {
      uint2 e; e.x = (u32)src[idx]; e.y = (u32)dst[idx];
      stage[i] = e;
      atomicAdd(&cnt[e.y >> 7], 1u);
    }
  }
  __syncthreads();
  for (int i = t; i < NBKT; i += 256) gcount[(size_t)i * nch + c] = (int)cnt[i];
  // blocked scan of cnt[NBKT]
  u32 ssum = 0;
  const int b0 = t * 4;  // 256*4 >= 782
#pragma unroll
  for (int j = 0; j < 4; ++j) {
    int i = b0 + j;
    if (i < NBKT) ssum += cnt[i];
  }
  sdata[t] = ssum;
  __syncthreads();
  for (int o = 1; o < 256; o <<= 1) {
    u32 x = (t >= o) ? sdata[t - o] : 0;
    __syncthreads();
    sdata[t] += x;
    __syncthreads();
  }
  u32 run = sdata[t] - ssum;
#pragma unroll
  for (int j = 0; j < 4; ++j) {
    int i = b0 + j;
    if (i < NBKT) { ofs[i] = run; run += cnt[i]; }
  }
  __syncthreads();
  for (int i = t; i < NBKT; i += 256) {
    lofs[(size_t)c * NBKT + i] = (int)ofs[i];
    cnt[i] = ofs[i];  // tickets
  }
  __syncthreads();
#pragma unroll
  for (int j = 0; j < 16; ++j) {
    int i = t + j * 256, idx = base + i;
    if (idx < E) {
      uint2 e = stage[i];
      u32 p = atomicAdd(&cnt[e.y >> 7], 1u);
      tmp[(size_t)base + p] = e;
    }
  }
}

// ---------------- sort pass 2: bucket -> exact sorted + deg + off ----------------
#define MAXB 2560
__global__ __launch_bounds__(256) void sort_pass2(
    const uint2* __restrict__ tmp, const int* __restrict__ prefix,
    const int* __restrict__ gcount, const int* __restrict__ lofs,
    int* __restrict__ outSorted, int* __restrict__ deg, int* __restrict__ offArr,
    int E, int nch, int n) {
  const int b = blockIdx.x, t = threadIdx.x;
  __shared__ u32 est[MAXB];
  __shared__ u32 outl[MAXB];
  __shared__ u32 cnt[128], ofs[128];
  __shared__ u32 sdata[256];

  const int node0 = b << 7;
  const int ebase = prefix[(size_t)b * nch];
  const int eend = (b == (int)gridDim.x - 1) ? E : prefix[(size_t)(b + 1) * nch];
  const int esize = eend - ebase;

  // gather this bucket's runs from every chunk
  for (int c = t; c < nch; c += 256) {
    int g = lofs[(size_t)c * NBKT + b];
    int len = gcount[(size_t)b * nch + c];
    int dp = prefix[(size_t)b * nch + c] - ebase;
    for (int k = 0; k < len; ++k) {
      uint2 e = tmp[(size_t)c * CHUNK + g + k];
      est[dp + k] = (e.x << 7) | (e.y & 127u);
    }
  }
  if (t < 128) cnt[t] = 0;
  __syncthreads();
  for (int i = t; i < esize; i += 256) atomicAdd(&cnt[est[i] & 127u], 1u);
  __syncthreads();
  // scan 128 counters (all 256 threads participate in log-scan)
  u32 v = (t < 128) ? cnt[t] : 0;
  sdata[t] = v;
  __syncthreads();
  for (int o = 1; o < 256; o <<= 1) {
    u32 x = (t >= o) ? sdata[t - o] : 0;
    __syncthreads();
    sdata[t] += x;
    __syncthreads();
  }
  if (t < 128) ofs[t] = sdata[t] - v;
  __syncthreads();
  const int nNodes = (n - node0) < 128 ? (n - node0) : 128;
  if (t < nNodes) {
    deg[node0 + t] = (int)cnt[t];
    offArr[node0 + t] = ebase + (int)ofs[t];
  }
  __syncthreads();
  if (t < 128) cnt[t] = ofs[t];  // tickets
  __syncthreads();
  for (int i = t; i < esize; i += 256) {
    u32 e = est[i];
    u32 p = atomicAdd(&cnt[e & 127u], 1u);
    outl[p] = e >> 7;
  }
  __syncthreads();
  for (int i = t; i < esize; i += 256) outSorted[ebase + i] = (int)outl[i];
}

// ---------------- f32 -> bf16 convert ----------------
__global__ void conv_bf16(const float* __restrict__ x, u16* __restrict__ o, int n8) {
  int i = blockIdx.x * blockDim.x + threadIdx.x;
  if (i >= n8) return;
  const float4* x4 = (const float4*)x;
  float4 v0 = x4[(size_t)i * 2];
  float4 v1 = x4[(size_t)i * 2 + 1];
  uint4 O;
  O.x = pack2(v0.x, v0.y);
  O.y = pack2(v0.z, v0.w);
  O.z = pack2(v1.x, v1.y);
  O.w = pack2(v1.z, v1.w);
  ((uint4*)o)[i] = O;
}

// ---------------- weight prep: W[K][N] -> Bt[Npad][K] bf16 ----------------
__global__ void prep_weight(const float* __restrict__ W, int K, int N, int Npad,
                            u16* __restrict__ Bt) {
  int idx = blockIdx.x * blockDim.x + threadIdx.x;
  int tot = Npad * K;
  if (idx >= tot) return;
  int n = idx / K, k = idx - n * K;
  float v = (n < N) ? W[(size_t)k * N + n] : 0.f;
  Bt[idx] = bf16_rn(v);
}

__global__ void pad_bias(const float* __restrict__ a, const float* __restrict__ b,
                         float* __restrict__ o, int n, int npad) {
  int i = blockIdx.x * blockDim.x + threadIdx.x;
  if (i < npad) o[i] = (i < n) ? (a[i] + (b ? b[i] : 0.f)) : 0.f;
}

// ---------------- node prep: dinv + author-mean (bf16 gather) ----------------
__global__ void node_prep(const u16* __restrict__ xa16,
                          const int* __restrict__ w_off, const int* __restrict__ w_cnt,
                          const int* __restrict__ w_sorted,
                          const int* __restrict__ deg_c,
                          u16* __restrict__ mean, float* __restrict__ dinv, int n) {
  int wave = (blockIdx.x * blockDim.x + threadIdx.x) >> 6;
  int lane = threadIdx.x & 63;
  if (wave >= n) return;
  int d = wave;
  int start = w_off[d];
  int cnt = w_cnt[d];
  float ax = 0.f, ay = 0.f;
  const unsigned* xa = (const unsigned*)xa16;  // row = 64 uints
  for (int j0 = 0; j0 < cnt; j0 += 64) {
    int nn = cnt - j0; nn = nn < 64 ? nn : 64;
    int sl = (j0 + lane < cnt) ? w_sorted[start + j0 + lane] : 0;
    int jj = 0;
    for (; jj + 4 <= nn; jj += 4) {
      int s0 = __shfl(sl, jj), s1 = __shfl(sl, jj + 1);
      int s2 = __shfl(sl, jj + 2), s3 = __shfl(sl, jj + 3);
      unsigned v0 = xa[(size_t)s0 * 64 + lane];
      unsigned v1 = xa[(size_t)s1 * 64 + lane];
      unsigned v2 = xa[(size_t)s2 * 64 + lane];
      unsigned v3 = xa[(size_t)s3 * 64 + lane];
      ax += bf16f((u16)v0) + bf16f((u16)v1) + bf16f((u16)v2) + bf16f((u16)v3);
      ay += bf16f((u16)(v0 >> 16)) + bf16f((u16)(v1 >> 16)) +
            bf16f((u16)(v2 >> 16)) + bf16f((u16)(v3 >> 16));
    }
    for (; jj < nn; ++jj) {
      int s = __shfl(sl, jj);
      unsigned v = xa[(size_t)s * 64 + lane];
      ax += bf16f((u16)v);
      ay += bf16f((u16)(v >> 16));
    }
  }
  float inv = 1.0f / (float)((cnt > 0) ? cnt : 1);
  ((unsigned*)mean)[(size_t)d * 64 + lane] = pack2(ax * inv, ay * inv);
  if (lane == 0) dinv[d] = rsqrtf((float)(deg_c[d] + 1));
}

// ---------------- GCN feature-space aggregation (wave per node, bf16 rows) ----
__global__ void agg_gcn(const u16* __restrict__ xin, const float* __restrict__ dinv,
                        const int* __restrict__ c_off, const int* __restrict__ c_cnt,
                        const int* __restrict__ c_sorted,
                        u16* __restrict__ xout, int n) {
  int wave = (blockIdx.x * blockDim.x + threadIdx.x) >> 6;
  int lane = threadIdx.x & 63;
  if (wave >= n) return;
  int d = wave;
  int start = c_off[d], cnt = c_cnt[d];
  float a0 = 0.f, a1 = 0.f, a2 = 0.f, a3 = 0.f;
  const uint2* base = (const uint2*)xin;  // row = 64 uint2 (512B)
  for (int j0 = 0; j0 < cnt; j0 += 64) {
    int nn = cnt - j0; nn = nn < 64 ? nn : 64;
    int sl = (j0 + lane < cnt) ? c_sorted[start + j0 + lane] : 0;
    int jj = 0;
    for (; jj + 4 <= nn; jj += 4) {
      int s0 = __shfl(sl, jj), s1 = __shfl(sl, jj + 1);
      int s2 = __shfl(sl, jj + 2), s3 = __shfl(sl, jj + 3);
      float d0 = dinv[s0], d1 = dinv[s1], d2 = dinv[s2], d3 = dinv[s3];
      uint2 v0 = base[(size_t)s0 * 64 + lane];
      uint2 v1 = base[(size_t)s1 * 64 + lane];
      uint2 v2 = base[(size_t)s2 * 64 + lane];
      uint2 v3 = base[(size_t)s3 * 64 + lane];
      a0 = fmaf(bf16f((u16)v0.x), d0, a0); a1 = fmaf(bf16f((u16)(v0.x >> 16)), d0, a1);
      a2 = fmaf(bf16f((u16)v0.y), d0, a2); a3 = fmaf(bf16f((u16)(v0.y >> 16)), d0, a3);
      a0 = fmaf(bf16f((u16)v1.x), d1, a0); a1 = fmaf(bf16f((u16)(v1.x >> 16)), d1, a1);
      a2 = fmaf(bf16f((u16)v1.y), d1, a2); a3 = fmaf(bf16f((u16)(v1.y >> 16)), d1, a3);
      a0 = fmaf(bf16f((u16)v2.x), d2, a0); a1 = fmaf(bf16f((u16)(v2.x >> 16)), d2, a1);
      a2 = fmaf(bf16f((u16)v2.y), d2, a2); a3 = fmaf(bf16f((u16)(v2.y >> 16)), d2, a3);
      a0 = fmaf(bf16f((u16)v3.x), d3, a0); a1 = fmaf(bf16f((u16)(v3.x >> 16)), d3, a1);
      a2 = fmaf(bf16f((u16)v3.y), d3, a2); a3 = fmaf(bf16f((u16)(v3.y >> 16)), d3, a3);
    }
    for (; jj < nn; ++jj) {
      int s = __shfl(sl, jj);
      float ds = dinv[s];
      uint2 v = base[(size_t)s * 64 + lane];
      a0 = fmaf(bf16f((u16)v.x), ds, a0); a1 = fmaf(bf16f((u16)(v.x >> 16)), ds, a1);
      a2 = fmaf(bf16f((u16)v.y), ds, a2); a3 = fmaf(bf16f((u16)(v.y >> 16)), ds, a3);
    }
  }
  float dd = dinv[d];
  {
    uint2 v = base[(size_t)d * 64 + lane];
    a0 = fmaf(bf16f((u16)v.x), dd, a0); a1 = fmaf(bf16f((u16)(v.x >> 16)), dd, a1);
    a2 = fmaf(bf16f((u16)v.y), dd, a2); a3 = fmaf(bf16f((u16)(v.y >> 16)), dd, a3);
  }
  uint2 O;
  O.x = pack2(a0 * dd, a1 * dd);
  O.y = pack2(a2 * dd, a3 * dd);
  ((uint2*)xout)[(size_t)d * 64 + lane] = O;
}

// ---------------- bf16 MFMA GEMM: tile 128 x 256, 8 waves (2x4) ----------------
template <int NSEG, bool F32OUT, int NC>
__global__ __launch_bounds__(512, 4) void gemm_bf16(
    const u16* __restrict__ A0, const u16* __restrict__ A1, const u16* __restrict__ A2,
    const u16* __restrict__ B0, const u16* __restrict__ B1, const u16* __restrict__ B2,
    const float* __restrict__ bias,
    u16* __restrict__ Cp, float* __restrict__ Cf,
    int M, int N) {
  __shared__ u16 Ah[2][4096];   // 128 rows x 32 k
  __shared__ u16 Bh[2][8192];   // 256 cols x 32 k

  const int t = threadIdx.x;
  const int wid = t >> 6, lane = t & 63;
  const int wr = wid >> 2, wc = wid & 3;
  const int lrow = lane & 15, kslot = lane >> 4;
  const int jsw = kslot ^ ((lrow >> 1) & 3);

  // bijective XCD-chunked block swizzle (m204), col-fastest
  const int nb = gridDim.x;
  const int q = nb >> 3, r = nb & 7;
  const int xcd = blockIdx.x & 7, pos = blockIdx.x >> 3;
  const int lin = (xcd < r ? xcd * (q + 1) : r * (q + 1) + (xcd - r) * q) + pos;
  const int bx = lin / NC, by = lin - bx * NC;
  const int gm = bx * 128;
  const int gn = by * 256;

  const int s_r = lane >> 2;
  const int s_j = (lane & 3) ^ ((s_r >> 1) & 3);

  f32x4 acc[4][4];
  const f32x4 z4 = {0.f, 0.f, 0.f, 0.f};
#pragma unroll
  for (int m = 0; m < 4; ++m)
#pragma unroll
    for (int n = 0; n < 4; ++n) acc[m][n] = z4;

  const int NT = (NSEG == 3) ? 20 : 8;

  auto STAGE = [&](int tt, int half) {
    const u16* A;
    const u16* B;
    int rs, k0;
    if (NSEG == 3 && tt >= 16)     { A = A2; B = B2; rs = 128; k0 = (tt - 16) * 32; }
    else if (NSEG == 3 && tt >= 8) { A = A1; B = B1; rs = 256; k0 = (tt - 8) * 32; }
    else                           { A = A0; B = B0; rs = 256; k0 = tt * 32; }
    {
      int grow = gm + wid * 16 + s_r;
      grow = grow < M ? grow : M - 1;
      gload16(A + (size_t)grow * rs + (k0 + s_j * 8), &Ah[half][wid * 512]);
    }
#pragma unroll
    for (int c = 0; c < 2; ++c) {
      int chunk = wid * 2 + c;
      int col = gn + chunk * 16 + s_r;
      gload16(B + (size_t)col * rs + (k0 + s_j * 8), &Bh[half][chunk * 512]);
    }
  };

  STAGE(0, 0);
  __syncthreads();

  for (int tt = 0; tt < NT; ++tt) {
    const int half = tt & 1;
    if (tt + 1 < NT) STAGE(tt + 1, half ^ 1);

    bf16x8 ah[4];
    const int ab = (wr * 64 + lrow) * 32 + jsw * 8;
#pragma unroll
    for (int m = 0; m < 4; ++m) ah[m] = *(const bf16x8*)&Ah[half][ab + m * 512];
    const int bb = (wc * 64 + lrow) * 32 + jsw * 8;
#pragma unroll
    for (int n = 0; n < 4; ++n) {
      bf16x8 bn = *(const bf16x8*)&Bh[half][bb + n * 512];
#pragma unroll
      for (int m = 0; m < 4; ++m)
        acc[m][n] = __builtin_amdgcn_mfma_f32_16x16x32_bf16(ah[m], bn, acc[m][n], 0, 0, 0);
    }
    __syncthreads();
  }

  // ---- epilogue ----
  const int col0 = gn + wc * 64 + lrow;
  const int row00 = gm + wr * 64 + kslot * 4;
#pragma unroll
  for (int m = 0; m < 4; ++m) {
#pragma unroll
    for (int i = 0; i < 4; ++i) {
      int row = row00 + m * 16 + i;
      if (row >= M) continue;
#pragma unroll
      for (int n = 0; n < 4; ++n) {
        int col = col0 + n * 16;
        float v = acc[m][n][i] + bias[col];
        if (F32OUT) {
          if (col < N) Cf[(size_t)row * N + col] = v;
        } else {
          Cp[(size_t)row * 256 + col] = bf16_rn(fmaxf(v, 0.f));
        }
      }
    }
  }
}

// ---------------- launch ----------------
static inline size_t align_up(size_t x) { return (x + 255) & ~(size_t)255; }

extern "C" void kernel_launch(void* const* d_in, const int* in_sizes, int n_in,
                              void* d_out, int out_size, void* d_ws, size_t ws_size,
                              hipStream_t stream) {
  const float* x_paper  = (const float*)d_in[0];
  const float* x_author = (const float*)d_in[1];
  const int*   cites    = (const int*)d_in[2];
  const int*   w_src    = (const int*)d_in[3];
  const int*   w_dst    = (const int*)d_in[4];
  const float* W1  = (const float*)d_in[5];
  const float* b1  = (const float*)d_in[6];
  const float* Wl1 = (const float*)d_in[7];
  const float* bl1 = (const float*)d_in[8];
  const float* Wr1 = (const float*)d_in[9];
  const float* W2  = (const float*)d_in[10];
  const float* b2  = (const float*)d_in[11];
  const float* Wl2 = (const float*)d_in[12];
  const float* bl2 = (const float*)d_in[13];
  const float* Wr2 = (const float*)d_in[14];
  const float* linW = (const float*)d_in[15];
  const float* linb = (const float*)d_in[16];
  float* out = (float*)d_out;

  const int N = in_sizes[0] / DP;       // 100000
  const int NA = in_sizes[1] / DA;      // 50000
  const int E = in_sizes[3];            // 1000000
  const int* c_src = cites;
  const int* c_dst = cites + E;

  const int NCH = (E + CHUNK - 1) / CHUNK;       // 245
  const int NB = (N + 127) >> 7;                 // 782 (== NBKT)
  const int GC = NB * NCH;                       // 191,590

  char* w = (char*)d_ws;
  size_t off = 0;
  auto alloc = [&](size_t bytes) -> void* {
    void* p = w + off;
    off = align_up(off + bytes);
    return p;
  };
  int* deg_c      = (int*)alloc((size_t)N * 4);
  int* cnt_w      = (int*)alloc((size_t)N * 4);
  int* cites_off  = (int*)alloc((size_t)N * 4);
  int* writes_off = (int*)alloc((size_t)N * 4);
  int* c_sorted   = (int*)alloc((size_t)E * 4);
  int* w_sorted   = (int*)alloc((size_t)E * 4);
  uint2* tmpE     = (uint2*)alloc((size_t)NCH * CHUNK * 8);
  int* gcount     = (int*)alloc((size_t)GC * 4);
  int* gprefix    = (int*)alloc((size_t)GC * 4);
  int* lofs       = (int*)alloc((size_t)NCH * NBKT * 4);
  int* bsumA      = (int*)alloc(256 * 4);
  float* dinv     = (float*)alloc((size_t)N * 4);
  u16* xa16       = (u16*)alloc((size_t)NA * DA * 2);
  u16* meanA      = (u16*)alloc((size_t)N * DA * 2);
  u16* xp         = (u16*)alloc((size_t)N * 256 * 2);
  u16* xs         = (u16*)alloc((size_t)N * 256 * 2);
  u16* pb         = (u16*)alloc((size_t)N * 256 * 2);
  const int bsW = 256 * 256, bsL = 256 * 128, bsLin = 512 * 256;
  u16* BtW1  = (u16*)alloc((size_t)bsW * 2);
  u16* BtWr1 = (u16*)alloc((size_t)bsW * 2);
  u16* BtW2  = (u16*)alloc((size_t)bsW * 2);
  u16* BtWr2 = (u16*)alloc((size_t)bsW * 2);
  u16* BtWl1 = (u16*)alloc((size_t)bsL * 2);
  u16* BtWl2 = (u16*)alloc((size_t)bsL * 2);
  u16* BtLin = (u16*)alloc((size_t)bsLin * 2);
  float* biasR1  = (float*)alloc(256 * 4);
  float* biasR2  = (float*)alloc(256 * 4);
  float* biasLin = (float*)alloc(512 * 4);
  (void)ws_size; (void)n_in; (void)out_size;

  const int nsb2 = (GC + SCAN_TILE - 1) / SCAN_TILE;  // 94

  // ---- cites CSR ----
  sort_pass1<<<NCH, 256, 0, stream>>>(c_src, c_dst, tmpE, gcount, lofs, E, NCH);
  scan_local<<<nsb2, SCAN_TPB, 0, stream>>>(gcount, gprefix, bsumA, GC);
  scan_spine<<<1, 256, 0, stream>>>(bsumA, nsb2);
  scan_add<<<nsb2, SCAN_TPB, 0, stream>>>(gprefix, bsumA, GC);
  sort_pass2<<<NB, 256, 0, stream>>>(tmpE, gprefix, gcount, lofs,
                                     c_sorted, deg_c, cites_off, E, NCH, N);

  // conversions (independent; also gives sort_pass2 writes time to settle L2)
  conv_bf16<<<(N * 32 + 255) / 256, 256, 0, stream>>>(x_paper, xp, N * 32);
  conv_bf16<<<(NA * 16 + 255) / 256, 256, 0, stream>>>(x_author, xa16, NA * 16);

  // ---- writes CSR (reuses tmp/gcount/gprefix/lofs) ----
  sort_pass1<<<NCH, 256, 0, stream>>>(w_src, w_dst, tmpE, gcount, lofs, E, NCH);
  scan_local<<<nsb2, SCAN_TPB, 0, stream>>>(gcount, gprefix, bsumA, GC);
  scan_spine<<<1, 256, 0, stream>>>(bsumA, nsb2);
  scan_add<<<nsb2, SCAN_TPB, 0, stream>>>(gprefix, bsumA, GC);
  sort_pass2<<<NB, 256, 0, stream>>>(tmpE, gprefix, gcount, lofs,
                                     w_sorted, cnt_w, writes_off, E, NCH, N);

  // weights / biases
  prep_weight<<<(bsW + 255) / 256, 256, 0, stream>>>(W1, 256, 256, 256, BtW1);
  prep_weight<<<(bsW + 255) / 256, 256, 0, stream>>>(Wr1, 256, 256, 256, BtWr1);
  prep_weight<<<(bsW + 255) / 256, 256, 0, stream>>>(W2, 256, 256, 256, BtW2);
  prep_weight<<<(bsW + 255) / 256, 256, 0, stream>>>(Wr2, 256, 256, 256, BtWr2);
  prep_weight<<<(bsL + 255) / 256, 256, 0, stream>>>(Wl1, 128, 256, 256, BtWl1);
  prep_weight<<<(bsL + 255) / 256, 256, 0, stream>>>(Wl2, 128, 256, 256, BtWl2);
  prep_weight<<<(bsLin + 255) / 256, 256, 0, stream>>>(linW, 256, DOUT, 512, BtLin);
  pad_bias<<<1, 256, 0, stream>>>(b1, bl1, biasR1, 256, 256);
  pad_bias<<<1, 256, 0, stream>>>(b2, bl2, biasR2, 256, 256);
  pad_bias<<<2, 256, 0, stream>>>(linb, nullptr, biasLin, DOUT, 512);

  int nbWave = (N * 64 + 255) / 256;
  node_prep<<<nbWave, 256, 0, stream>>>(xa16, writes_off, cnt_w, w_sorted,
                                        deg_c, meanA, dinv, N);

  const int GX = (N + 127) / 128;  // 782

  // layer 1
  agg_gcn<<<nbWave, 256, 0, stream>>>(xp, dinv, cites_off, deg_c, c_sorted, xs, N);
  gemm_bf16<3, false, 1><<<GX, 512, 0, stream>>>(
      xs, xp, meanA, BtW1, BtWr1, BtWl1, biasR1, pb, nullptr, N, HIDN);
  // layer 2
  agg_gcn<<<nbWave, 256, 0, stream>>>(pb, dinv, cites_off, deg_c, c_sorted, xs, N);
  gemm_bf16<3, false, 1><<<GX, 512, 0, stream>>>(
      xs, pb, meanA, BtW2, BtWr2, BtWl2, biasR2, xp, nullptr, N, HIDN);
  // output projection (2 col tiles of 256, masked to 349)
  gemm_bf16<1, true, 2><<<GX * 2, 512, 0, stream>>>(
      xp, nullptr, nullptr, BtLin, nullptr, nullptr, biasLin, nullptr, out, N, DOUT);
}

// Round 8
// 493.242 us; speedup vs baseline: 2.6264x; 1.0993x over previous
//
#include <hip/hip_runtime.h>

// HeteroGNN on MI355X — round 8: m97-shape GEMMs (128x128, 4-wave, 32KB LDS),
// 384-padded final projection (3x128 col tiles), fused dual-edge-type sort,
// fused node_prep+agg layer 1. dinv computed in sort_pass2(cites).

#define DP   256
#define DA   128
#define HIDN 256
#define DOUT 349
#define NBKT 782          // ceil(100000/128)
#define CHUNK 4096

typedef unsigned short u16;
typedef unsigned int u32;
typedef __attribute__((ext_vector_type(8))) short bf16x8;
typedef __attribute__((ext_vector_type(4))) float f32x4;

__device__ __forceinline__ u16 bf16_rn(float x) {
  union { float f; unsigned u; } v; v.f = x;
  unsigned r = v.u + 0x7FFFu + ((v.u >> 16) & 1u);
  return (u16)(r >> 16);
}
__device__ __forceinline__ float bf16f(u16 h) {
  union { float f; unsigned u; } v; v.u = ((unsigned)h) << 16; return v.f;
}
__device__ __forceinline__ unsigned pack2(float a, float b) {
  return (unsigned)bf16_rn(a) | ((unsigned)bf16_rn(b) << 16);
}

__device__ __forceinline__ void gload16(const void* g, void* lds) {
  __builtin_amdgcn_global_load_lds(
      (const __attribute__((address_space(1))) unsigned int*)g,
      (__attribute__((address_space(3))) unsigned int*)lds, 16, 0, 0);
}

// ---------------- exclusive scan (2048/block) ----------------
#define SCAN_TPB 256
#define SCAN_VPT 8
#define SCAN_TILE 2048

__global__ void scan_local(const int* __restrict__ in, int* __restrict__ out,
                           int* __restrict__ bsum, int n) {
  __shared__ int sdata[SCAN_TPB];
  int t = threadIdx.x;
  int base = blockIdx.x * SCAN_TILE + t * SCAN_VPT;
  int v[SCAN_VPT];
  int sum = 0;
#pragma unroll
  for (int j = 0; j < SCAN_VPT; ++j) {
    int idx = base + j;
    v[j] = (idx < n) ? in[idx] : 0;
    sum += v[j];
  }
  sdata[t] = sum;
  __syncthreads();
  for (int off = 1; off < SCAN_TPB; off <<= 1) {
    int x = (t >= off) ? sdata[t - off] : 0;
    __syncthreads();
    sdata[t] += x;
    __syncthreads();
  }
  int prefix = sdata[t] - sum;
  if (t == SCAN_TPB - 1) bsum[blockIdx.x] = sdata[t];
  int run = prefix;
#pragma unroll
  for (int j = 0; j < SCAN_VPT; ++j) {
    int idx = base + j;
    if (idx < n) out[idx] = run;
    run += v[j];
  }
}

__global__ void scan_spine(int* __restrict__ bsum, int nb) {
  __shared__ int sdata[256];
  int t = threadIdx.x;
  int v = (t < nb) ? bsum[t] : 0;
  sdata[t] = v;
  __syncthreads();
  for (int off = 1; off < 256; off <<= 1) {
    int x = (t >= off) ? sdata[t - off] : 0;
    __syncthreads();
    sdata[t] += x;
    __syncthreads();
  }
  if (t < nb) bsum[t] = sdata[t] - v;
}

__global__ void scan_add(int* __restrict__ out, const int* __restrict__ bsum, int n) {
  int add = bsum[blockIdx.x];
  int base = blockIdx.x * SCAN_TILE + threadIdx.x * SCAN_VPT;
#pragma unroll
  for (int j = 0; j < SCAN_VPT; ++j) {
    int idx = base + j;
    if (idx < n) out[idx] += add;
  }
}

// -------- sort pass 1 (both edge types in one launch): chunk -> bucketed tmp ----
// counts layout: [et][bucket][chunk]; lofs layout: [et][chunk][bucket]
__global__ __launch_bounds__(256) void sort_pass1(
    const int* __restrict__ c_src, const int* __restrict__ c_dst,
    const int* __restrict__ w_srcP, const int* __restrict__ w_dstP,
    uint2* __restrict__ tmp, int* __restrict__ gcount, int* __restrict__ lofs,
    int E, int nch) {
  const int cg = blockIdx.x, t = threadIdx.x;
  const int et = cg >= nch;
  const int c = cg - et * nch;
  const int* src = et ? w_srcP : c_src;
  const int* dst = et ? w_dstP : c_dst;
  __shared__ u32 cnt[NBKT];
  __shared__ u32 ofs[NBKT];
  __shared__ u32 sdata[256];
  __shared__ uint2 stage[CHUNK];

  for (int i = t; i < NBKT; i += 256) cnt[i] = 0;
  __syncthreads();
  const int base = c * CHUNK;
#pragma unroll
  for (int j = 0; j < 16; ++j) {
    int i = t + j * 256, idx = base + i;
    if (idx < E) {
      uint2 e; e.x = (u32)src[idx]; e.y = (u32)dst[idx];
      stage[i] = e;
      atomicAdd(&cnt[e.y >> 7], 1u);
    }
  }
  __syncthreads();
  for (int i = t; i < NBKT; i += 256)
    gcount[((size_t)et * NBKT + i) * nch + c] = (int)cnt[i];
  u32 ssum = 0;
  const int b0 = t * 4;
#pragma unroll
  for (int j = 0; j < 4; ++j) {
    int i = b0 + j;
    if (i < NBKT) ssum += cnt[i];
  }
  sdata[t] = ssum;
  __syncthreads();
  for (int o = 1; o < 256; o <<= 1) {
    u32 x = (t >= o) ? sdata[t - o] : 0;
    __syncthreads();
    sdata[t] += x;
    __syncthreads();
  }
  u32 run = sdata[t] - ssum;
#pragma unroll
  for (int j = 0; j < 4; ++j) {
    int i = b0 + j;
    if (i < NBKT) { ofs[i] = run; run += cnt[i]; }
  }
  __syncthreads();
  for (int i = t; i < NBKT; i += 256) {
    lofs[((size_t)et * nch + c) * NBKT + i] = (int)ofs[i];
    cnt[i] = ofs[i];
  }
  __syncthreads();
  uint2* tout = tmp + (size_t)et * nch * CHUNK + base;
#pragma unroll
  for (int j = 0; j < 16; ++j) {
    int i = t + j * 256, idx = base + i;
    if (idx < E) {
      uint2 e = stage[i];
      u32 p = atomicAdd(&cnt[e.y >> 7], 1u);
      tout[p] = e;
    }
  }
}

// -------- sort pass 2 (both edge types): bucket -> sorted + deg + off (+dinv) ---
#define MAXB 2560
__global__ __launch_bounds__(256) void sort_pass2(
    const uint2* __restrict__ tmp, const int* __restrict__ prefix,
    const int* __restrict__ gcount, const int* __restrict__ lofs,
    int* __restrict__ cSorted, int* __restrict__ cDeg, int* __restrict__ cOff,
    int* __restrict__ wSorted, int* __restrict__ wDeg, int* __restrict__ wOff,
    float* __restrict__ dinv,
    int E, int nch, int n, int nbk) {
  const int bg = blockIdx.x, t = threadIdx.x;
  const int et = bg >= nbk;
  const int b = bg - et * nbk;
  int* outSorted = et ? wSorted : cSorted;
  int* deg = et ? wDeg : cDeg;
  int* offArr = et ? wOff : cOff;
  __shared__ u32 est[MAXB];
  __shared__ u32 outl[MAXB];
  __shared__ u32 cnt[128], ofs[128];
  __shared__ u32 sdata[256];

  const int node0 = b << 7;
  const size_t bgl = (size_t)et * NBKT + b;
  const int ebaseG = prefix[bgl * nch];
  const int eendG = (bg == 2 * nbk - 1) ? 2 * E : prefix[(bgl + 1) * nch];
  const int ebase = ebaseG - et * E;
  const int esize = (eendG - et * E) - ebase;

  const uint2* tsrc = tmp + (size_t)et * nch * CHUNK;
  for (int c = t; c < nch; c += 256) {
    int g = lofs[((size_t)et * nch + c) * NBKT + b];
    int len = gcount[bgl * nch + c];
    int dp = prefix[bgl * nch + c] - ebaseG;
    for (int k = 0; k < len; ++k) {
      uint2 e = tsrc[(size_t)c * CHUNK + g + k];
      est[dp + k] = (e.x << 7) | (e.y & 127u);
    }
  }
  if (t < 128) cnt[t] = 0;
  __syncthreads();
  for (int i = t; i < esize; i += 256) atomicAdd(&cnt[est[i] & 127u], 1u);
  __syncthreads();
  u32 v = (t < 128) ? cnt[t] : 0;
  sdata[t] = v;
  __syncthreads();
  for (int o = 1; o < 256; o <<= 1) {
    u32 x = (t >= o) ? sdata[t - o] : 0;
    __syncthreads();
    sdata[t] += x;
    __syncthreads();
  }
  if (t < 128) ofs[t] = sdata[t] - v;
  __syncthreads();
  const int nNodes = (n - node0) < 128 ? (n - node0) : 128;
  if (t < nNodes) {
    deg[node0 + t] = (int)cnt[t];
    offArr[node0 + t] = ebase + (int)ofs[t];
    if (et == 0) dinv[node0 + t] = rsqrtf((float)(cnt[t] + 1));
  }
  __syncthreads();
  if (t < 128) cnt[t] = ofs[t];
  __syncthreads();
  for (int i = t; i < esize; i += 256) {
    u32 e = est[i];
    u32 p = atomicAdd(&cnt[e & 127u], 1u);
    outl[p] = e >> 7;
  }
  __syncthreads();
  for (int i = t; i < esize; i += 256) outSorted[ebase + i] = (int)outl[i];
}

// ---------------- f32 -> bf16 convert ----------------
__global__ void conv_bf16(const float* __restrict__ x, u16* __restrict__ o, int n8) {
  int i = blockIdx.x * blockDim.x + threadIdx.x;
  if (i >= n8) return;
  const float4* x4 = (const float4*)x;
  float4 v0 = x4[(size_t)i * 2];
  float4 v1 = x4[(size_t)i * 2 + 1];
  uint4 O;
  O.x = pack2(v0.x, v0.y);
  O.y = pack2(v0.z, v0.w);
  O.z = pack2(v1.x, v1.y);
  O.w = pack2(v1.z, v1.w);
  ((uint4*)o)[i] = O;
}

// ---------------- weight prep: W[K][N] -> Bt[Npad][K] bf16 ----------------
__global__ void prep_weight(const float* __restrict__ W, int K, int N, int Npad,
                            u16* __restrict__ Bt) {
  int idx = blockIdx.x * blockDim.x + threadIdx.x;
  int tot = Npad * K;
  if (idx >= tot) return;
  int n = idx / K, k = idx - n * K;
  float v = (n < N) ? W[(size_t)k * N + n] : 0.f;
  Bt[idx] = bf16_rn(v);
}

__global__ void pad_bias(const float* __restrict__ a, const float* __restrict__ b,
                         float* __restrict__ o, int n, int npad) {
  int i = blockIdx.x * blockDim.x + threadIdx.x;
  if (i < npad) o[i] = (i < n) ? (a[i] + (b ? b[i] : 0.f)) : 0.f;
}

// -------- fused gather: blocks [0,nbw) = agg_gcn layer1; [nbw,2*nbw) = node_prep
__global__ void gather_fused(
    const u16* __restrict__ xin, const float* __restrict__ dinv,
    const int* __restrict__ c_off, const int* __restrict__ c_cnt,
    const int* __restrict__ c_sorted, u16* __restrict__ xout,
    const u16* __restrict__ xa16, const int* __restrict__ w_off,
    const int* __restrict__ w_cnt, const int* __restrict__ w_sorted,
    u16* __restrict__ mean, int n, int nbw) {
  const int lane = threadIdx.x & 63;
  if (blockIdx.x < nbw) {
    int wave = ((blockIdx.x * blockDim.x) >> 6) + (threadIdx.x >> 6);
    if (wave >= n) return;
    int d = wave;
    int start = c_off[d], cnt = c_cnt[d];
    float a0 = 0.f, a1 = 0.f, a2 = 0.f, a3 = 0.f;
    const uint2* base = (const uint2*)xin;
    for (int j0 = 0; j0 < cnt; j0 += 64) {
      int nn = cnt - j0; nn = nn < 64 ? nn : 64;
      int sl = (j0 + lane < cnt) ? c_sorted[start + j0 + lane] : 0;
      int jj = 0;
      for (; jj + 4 <= nn; jj += 4) {
        int s0 = __shfl(sl, jj), s1 = __shfl(sl, jj + 1);
        int s2 = __shfl(sl, jj + 2), s3 = __shfl(sl, jj + 3);
        float d0 = dinv[s0], d1 = dinv[s1], d2 = dinv[s2], d3 = dinv[s3];
        uint2 v0 = base[(size_t)s0 * 64 + lane];
        uint2 v1 = base[(size_t)s1 * 64 + lane];
        uint2 v2 = base[(size_t)s2 * 64 + lane];
        uint2 v3 = base[(size_t)s3 * 64 + lane];
        a0 = fmaf(bf16f((u16)v0.x), d0, a0); a1 = fmaf(bf16f((u16)(v0.x >> 16)), d0, a1);
        a2 = fmaf(bf16f((u16)v0.y), d0, a2); a3 = fmaf(bf16f((u16)(v0.y >> 16)), d0, a3);
        a0 = fmaf(bf16f((u16)v1.x), d1, a0); a1 = fmaf(bf16f((u16)(v1.x >> 16)), d1, a1);
        a2 = fmaf(bf16f((u16)v1.y), d1, a2); a3 = fmaf(bf16f((u16)(v1.y >> 16)), d1, a3);
        a0 = fmaf(bf16f((u16)v2.x), d2, a0); a1 = fmaf(bf16f((u16)(v2.x >> 16)), d2, a1);
        a2 = fmaf(bf16f((u16)v2.y), d2, a2); a3 = fmaf(bf16f((u16)(v2.y >> 16)), d2, a3);
        a0 = fmaf(bf16f((u16)v3.x), d3, a0); a1 = fmaf(bf16f((u16)(v3.x >> 16)), d3, a1);
        a2 = fmaf(bf16f((u16)v3.y), d3, a2); a3 = fmaf(bf16f((u16)(v3.y >> 16)), d3, a3);
      }
      for (; jj < nn; ++jj) {
        int s = __shfl(sl, jj);
        float ds = dinv[s];
        uint2 v = base[(size_t)s * 64 + lane];
        a0 = fmaf(bf16f((u16)v.x), ds, a0); a1 = fmaf(bf16f((u16)(v.x >> 16)), ds, a1);
        a2 = fmaf(bf16f((u16)v.y), ds, a2); a3 = fmaf(bf16f((u16)(v.y >> 16)), ds, a3);
      }
    }
    float dd = dinv[d];
    {
      uint2 v = base[(size_t)d * 64 + lane];
      a0 = fmaf(bf16f((u16)v.x), dd, a0); a1 = fmaf(bf16f((u16)(v.x >> 16)), dd, a1);
      a2 = fmaf(bf16f((u16)v.y), dd, a2); a3 = fmaf(bf16f((u16)(v.y >> 16)), dd, a3);
    }
    uint2 O;
    O.x = pack2(a0 * dd, a1 * dd);
    O.y = pack2(a2 * dd, a3 * dd);
    ((uint2*)xout)[(size_t)d * 64 + lane] = O;
  } else {
    int wave = (((blockIdx.x - nbw) * blockDim.x) >> 6) + (threadIdx.x >> 6);
    if (wave >= n) return;
    int d = wave;
    int start = w_off[d];
    int cnt = w_cnt[d];
    float ax = 0.f, ay = 0.f;
    const unsigned* xa = (const unsigned*)xa16;
    for (int j0 = 0; j0 < cnt; j0 += 64) {
      int nn = cnt - j0; nn = nn < 64 ? nn : 64;
      int sl = (j0 + lane < cnt) ? w_sorted[start + j0 + lane] : 0;
      int jj = 0;
      for (; jj + 4 <= nn; jj += 4) {
        int s0 = __shfl(sl, jj), s1 = __shfl(sl, jj + 1);
        int s2 = __shfl(sl, jj + 2), s3 = __shfl(sl, jj + 3);
        unsigned v0 = xa[(size_t)s0 * 64 + lane];
        unsigned v1 = xa[(size_t)s1 * 64 + lane];
        unsigned v2 = xa[(size_t)s2 * 64 + lane];
        unsigned v3 = xa[(size_t)s3 * 64 + lane];
        ax += bf16f((u16)v0) + bf16f((u16)v1) + bf16f((u16)v2) + bf16f((u16)v3);
        ay += bf16f((u16)(v0 >> 16)) + bf16f((u16)(v1 >> 16)) +
              bf16f((u16)(v2 >> 16)) + bf16f((u16)(v3 >> 16));
      }
      for (; jj < nn; ++jj) {
        int s = __shfl(sl, jj);
        unsigned v = xa[(size_t)s * 64 + lane];
        ax += bf16f((u16)v);
        ay += bf16f((u16)(v >> 16));
      }
    }
    float inv = 1.0f / (float)((cnt > 0) ? cnt : 1);
    ((unsigned*)mean)[(size_t)d * 64 + lane] = pack2(ax * inv, ay * inv);
  }
}

// ---------------- agg_gcn standalone (layer 2) ----------------
__global__ void agg_gcn(const u16* __restrict__ xin, const float* __restrict__ dinv,
                        const int* __restrict__ c_off, const int* __restrict__ c_cnt,
                        const int* __restrict__ c_sorted,
                        u16* __restrict__ xout, int n) {
  int wave = (blockIdx.x * blockDim.x + threadIdx.x) >> 6;
  int lane = threadIdx.x & 63;
  if (wave >= n) return;
  int d = wave;
  int start = c_off[d], cnt = c_cnt[d];
  float a0 = 0.f, a1 = 0.f, a2 = 0.f, a3 = 0.f;
  const uint2* base = (const uint2*)xin;
  for (int j0 = 0; j0 < cnt; j0 += 64) {
    int nn = cnt - j0; nn = nn < 64 ? nn : 64;
    int sl = (j0 + lane < cnt) ? c_sorted[start + j0 + lane] : 0;
    int jj = 0;
    for (; jj + 4 <= nn; jj += 4) {
      int s0 = __shfl(sl, jj), s1 = __shfl(sl, jj + 1);
      int s2 = __shfl(sl, jj + 2), s3 = __shfl(sl, jj + 3);
      float d0 = dinv[s0], d1 = dinv[s1], d2 = dinv[s2], d3 = dinv[s3];
      uint2 v0 = base[(size_t)s0 * 64 + lane];
      uint2 v1 = base[(size_t)s1 * 64 + lane];
      uint2 v2 = base[(size_t)s2 * 64 + lane];
      uint2 v3 = base[(size_t)s3 * 64 + lane];
      a0 = fmaf(bf16f((u16)v0.x), d0, a0); a1 = fmaf(bf16f((u16)(v0.x >> 16)), d0, a1);
      a2 = fmaf(bf16f((u16)v0.y), d0, a2); a3 = fmaf(bf16f((u16)(v0.y >> 16)), d0, a3);
      a0 = fmaf(bf16f((u16)v1.x), d1, a0); a1 = fmaf(bf16f((u16)(v1.x >> 16)), d1, a1);
      a2 = fmaf(bf16f((u16)v1.y), d1, a2); a3 = fmaf(bf16f((u16)(v1.y >> 16)), d1, a3);
      a0 = fmaf(bf16f((u16)v2.x), d2, a0); a1 = fmaf(bf16f((u16)(v2.x >> 16)), d2, a1);
      a2 = fmaf(bf16f((u16)v2.y), d2, a2); a3 = fmaf(bf16f((u16)(v2.y >> 16)), d2, a3);
      a0 = fmaf(bf16f((u16)v3.x), d3, a0); a1 = fmaf(bf16f((u16)(v3.x >> 16)), d3, a1);
      a2 = fmaf(bf16f((u16)v3.y), d3, a2); a3 = fmaf(bf16f((u16)(v3.y >> 16)), d3, a3);
    }
    for (; jj < nn; ++jj) {
      int s = __shfl(sl, jj);
      float ds = dinv[s];
      uint2 v = base[(size_t)s * 64 + lane];
      a0 = fmaf(bf16f((u16)v.x), ds, a0); a1 = fmaf(bf16f((u16)(v.x >> 16)), ds, a1);
      a2 = fmaf(bf16f((u16)v.y), ds, a2); a3 = fmaf(bf16f((u16)(v.y >> 16)), ds, a3);
    }
  }
  float dd = dinv[d];
  {
    uint2 v = base[(size_t)d * 64 + lane];
    a0 = fmaf(bf16f((u16)v.x), dd, a0); a1 = fmaf(bf16f((u16)(v.x >> 16)), dd, a1);
    a2 = fmaf(bf16f((u16)v.y), dd, a2); a3 = fmaf(bf16f((u16)(v.y >> 16)), dd, a3);
  }
  uint2 O;
  O.x = pack2(a0 * dd, a1 * dd);
  O.y = pack2(a2 * dd, a3 * dd);
  ((uint2*)xout)[(size_t)d * 64 + lane] = O;
}

// ------------- bf16 MFMA GEMM: tile 128x128, 4 waves (2x2), 32KB LDS ----------
// NSEG=3: C = A0@B0 + A1@B1 + A2@B2(K=128) + bias -> relu -> bf16 [M][256]
// NSEG=1: C = A0@B0 + bias -> f32 [M][N] (col-masked). NC col tiles of 128.
template <int NSEG, bool F32OUT, int NC>
__global__ __launch_bounds__(256, 4) void gemm_bf16(
    const u16* __restrict__ A0, const u16* __restrict__ A1, const u16* __restrict__ A2,
    const u16* __restrict__ B0, const u16* __restrict__ B1, const u16* __restrict__ B2,
    const float* __restrict__ bias,
    u16* __restrict__ Cp, float* __restrict__ Cf,
    int M, int N) {
  __shared__ u16 Ah[2][4096];   // 128 rows x 32 k
  __shared__ u16 Bh[2][4096];   // 128 cols x 32 k

  const int t = threadIdx.x;
  const int wid = t >> 6, lane = t & 63;
  const int wr = wid >> 1, wc = wid & 1;
  const int lrow = lane & 15, kslot = lane >> 4;
  const int jsw = kslot ^ ((lrow >> 1) & 3);

  // bijective XCD-chunked block swizzle (m204), col-fastest
  const int nb = gridDim.x;
  const int q = nb >> 3, r = nb & 7;
  const int xcd = blockIdx.x & 7, pos = blockIdx.x >> 3;
  const int lin = (xcd < r ? xcd * (q + 1) : r * (q + 1) + (xcd - r) * q) + pos;
  const int bx = lin / NC, by = lin - bx * NC;
  const int gm = bx * 128;
  const int gn = by * 128;

  const int s_r = lane >> 2;
  const int s_j = (lane & 3) ^ ((s_r >> 1) & 3);

  f32x4 acc[4][4];
  const f32x4 z4 = {0.f, 0.f, 0.f, 0.f};
#pragma unroll
  for (int m = 0; m < 4; ++m)
#pragma unroll
    for (int n = 0; n < 4; ++n) acc[m][n] = z4;

  const int NT = (NSEG == 3) ? 20 : 8;

  auto STAGE = [&](int tt, int half) {
    const u16* A;
    const u16* B;
    int rs, k0;
    if (NSEG == 3 && tt >= 16)     { A = A2; B = B2; rs = 128; k0 = (tt - 16) * 32; }
    else if (NSEG == 3 && tt >= 8) { A = A1; B = B1; rs = 256; k0 = (tt - 8) * 32; }
    else                           { A = A0; B = B0; rs = 256; k0 = tt * 32; }
    const int c = wid * 2;
#pragma unroll
    for (int cc = 0; cc < 2; ++cc) {
      int grow = gm + (c + cc) * 16 + s_r;
      grow = grow < M ? grow : M - 1;
      gload16(A + (size_t)grow * rs + (k0 + s_j * 8), &Ah[half][(c + cc) * 512]);
      int col = gn + (c + cc) * 16 + s_r;
      gload16(B + (size_t)col * rs + (k0 + s_j * 8), &Bh[half][(c + cc) * 512]);
    }
  };

  STAGE(0, 0);
  __syncthreads();

  for (int tt = 0; tt < NT; ++tt) {
    const int half = tt & 1;
    if (tt + 1 < NT) STAGE(tt + 1, half ^ 1);

    bf16x8 ah[4];
    const int ab = (wr * 64 + lrow) * 32 + jsw * 8;
#pragma unroll
    for (int m = 0; m < 4; ++m) ah[m] = *(const bf16x8*)&Ah[half][ab + m * 512];
    const int bb = (wc * 64 + lrow) * 32 + jsw * 8;
#pragma unroll
    for (int n = 0; n < 4; ++n) {
      bf16x8 bn = *(const bf16x8*)&Bh[half][bb + n * 512];
#pragma unroll
      for (int m = 0; m < 4; ++m)
        acc[m][n] = __builtin_amdgcn_mfma_f32_16x16x32_bf16(ah[m], bn, acc[m][n], 0, 0, 0);
    }
    __syncthreads();
  }

  // ---- epilogue ----
  const int col0 = gn + wc * 64 + lrow;
  const int row00 = gm + wr * 64 + kslot * 4;
#pragma unroll
  for (int m = 0; m < 4; ++m) {
#pragma unroll
    for (int i = 0; i < 4; ++i) {
      int row = row00 + m * 16 + i;
      if (row >= M) continue;
#pragma unroll
      for (int n = 0; n < 4; ++n) {
        int col = col0 + n * 16;
        float v = acc[m][n][i] + bias[col];
        if (F32OUT) {
          if (col < N) Cf[(size_t)row * N + col] = v;
        } else {
          Cp[(size_t)row * 256 + col] = bf16_rn(fmaxf(v, 0.f));
        }
      }
    }
  }
}

// ---------------- launch ----------------
static inline size_t align_up(size_t x) { return (x + 255) & ~(size_t)255; }

extern "C" void kernel_launch(void* const* d_in, const int* in_sizes, int n_in,
                              void* d_out, int out_size, void* d_ws, size_t ws_size,
                              hipStream_t stream) {
  const float* x_paper  = (const float*)d_in[0];
  const float* x_author = (const float*)d_in[1];
  const int*   cites    = (const int*)d_in[2];
  const int*   w_src    = (const int*)d_in[3];
  const int*   w_dst    = (const int*)d_in[4];
  const float* W1  = (const float*)d_in[5];
  const float* b1  = (const float*)d_in[6];
  const float* Wl1 = (const float*)d_in[7];
  const float* bl1 = (const float*)d_in[8];
  const float* Wr1 = (const float*)d_in[9];
  const float* W2  = (const float*)d_in[10];
  const float* b2  = (const float*)d_in[11];
  const float* Wl2 = (const float*)d_in[12];
  const float* bl2 = (const float*)d_in[13];
  const float* Wr2 = (const float*)d_in[14];
  const float* linW = (const float*)d_in[15];
  const float* linb = (const float*)d_in[16];
  float* out = (float*)d_out;

  const int N = in_sizes[0] / DP;       // 100000
  const int NA = in_sizes[1] / DA;      // 50000
  const int E = in_sizes[3];            // 1000000
  const int* c_src = cites;
  const int* c_dst = cites + E;

  const int NCH = (E + CHUNK - 1) / CHUNK;       // 245
  const int NB = (N + 127) >> 7;                 // 782
  const int GC2 = 2 * NB * NCH;                  // both edge types

  char* w = (char*)d_ws;
  size_t off = 0;
  auto alloc = [&](size_t bytes) -> void* {
    void* p = w + off;
    off = align_up(off + bytes);
    return p;
  };
  int* deg_c      = (int*)alloc((size_t)N * 4);
  int* cnt_w      = (int*)alloc((size_t)N * 4);
  int* cites_off  = (int*)alloc((size_t)N * 4);
  int* writes_off = (int*)alloc((size_t)N * 4);
  int* c_sorted   = (int*)alloc((size_t)E * 4);
  int* w_sorted   = (int*)alloc((size_t)E * 4);
  uint2* tmpE     = (uint2*)alloc((size_t)2 * NCH * CHUNK * 8);
  int* gcount     = (int*)alloc((size_t)GC2 * 4);
  int* gprefix    = (int*)alloc((size_t)GC2 * 4);
  int* lofs       = (int*)alloc((size_t)2 * NCH * NBKT * 4);
  int* bsumA      = (int*)alloc(256 * 4);
  float* dinv     = (float*)alloc((size_t)N * 4);
  u16* xa16       = (u16*)alloc((size_t)NA * DA * 2);
  u16* meanA      = (u16*)alloc((size_t)N * DA * 2);
  u16* xp         = (u16*)alloc((size_t)N * 256 * 2);
  u16* xs         = (u16*)alloc((size_t)N * 256 * 2);
  u16* pb         = (u16*)alloc((size_t)N * 256 * 2);
  const int bsW = 256 * 256, bsL = 256 * 128, bsLin = 384 * 256;
  u16* BtW1  = (u16*)alloc((size_t)bsW * 2);
  u16* BtWr1 = (u16*)alloc((size_t)bsW * 2);
  u16* BtW2  = (u16*)alloc((size_t)bsW * 2);
  u16* BtWr2 = (u16*)alloc((size_t)bsW * 2);
  u16* BtWl1 = (u16*)alloc((size_t)bsL * 2);
  u16* BtWl2 = (u16*)alloc((size_t)bsL * 2);
  u16* BtLin = (u16*)alloc((size_t)bsLin * 2);
  float* biasR1  = (float*)alloc(256 * 4);
  float* biasR2  = (float*)alloc(256 * 4);
  float* biasLin = (float*)alloc(384 * 4);
  (void)ws_size; (void)n_in; (void)out_size;

  const int nsb2 = (GC2 + SCAN_TILE - 1) / SCAN_TILE;  // 188

  // ---- fused CSR build (both edge types) ----
  sort_pass1<<<2 * NCH, 256, 0, stream>>>(c_src, c_dst, w_src, w_dst,
                                          tmpE, gcount, lofs, E, NCH);
  scan_local<<<nsb2, SCAN_TPB, 0, stream>>>(gcount, gprefix, bsumA, GC2);
  scan_spine<<<1, 256, 0, stream>>>(bsumA, nsb2);
  scan_add<<<nsb2, SCAN_TPB, 0, stream>>>(gprefix, bsumA, GC2);
  sort_pass2<<<2 * NB, 256, 0, stream>>>(tmpE, gprefix, gcount, lofs,
                                         c_sorted, deg_c, cites_off,
                                         w_sorted, cnt_w, writes_off,
                                         dinv, E, NCH, N, NB);

  // conversions
  conv_bf16<<<(N * 32 + 255) / 256, 256, 0, stream>>>(x_paper, xp, N * 32);
  conv_bf16<<<(NA * 16 + 255) / 256, 256, 0, stream>>>(x_author, xa16, NA * 16);

  // weights / biases
  prep_weight<<<(bsW + 255) / 256, 256, 0, stream>>>(W1, 256, 256, 256, BtW1);
  prep_weight<<<(bsW + 255) / 256, 256, 0, stream>>>(Wr1, 256, 256, 256, BtWr1);
  prep_weight<<<(bsW + 255) / 256, 256, 0, stream>>>(W2, 256, 256, 256, BtW2);
  prep_weight<<<(bsW + 255) / 256, 256, 0, stream>>>(Wr2, 256, 256, 256, BtWr2);
  prep_weight<<<(bsL + 255) / 256, 256, 0, stream>>>(Wl1, 128, 256, 256, BtWl1);
  prep_weight<<<(bsL + 255) / 256, 256, 0, stream>>>(Wl2, 128, 256, 256, BtWl2);
  prep_weight<<<(bsLin + 255) / 256, 256, 0, stream>>>(linW, 256, DOUT, 384, BtLin);
  pad_bias<<<1, 256, 0, stream>>>(b1, bl1, biasR1, 256, 256);
  pad_bias<<<1, 256, 0, stream>>>(b2, bl2, biasR2, 256, 256);
  pad_bias<<<2, 256, 0, stream>>>(linb, nullptr, biasLin, DOUT, 384);

  const int nbWave = (N * 64 + 255) / 256;
  const int GX = (N + 127) / 128;  // 782

  // layer 1: fused agg(cites,xp->xs) + node_prep(writes,xa16->meanA)
  gather_fused<<<2 * nbWave, 256, 0, stream>>>(
      xp, dinv, cites_off, deg_c, c_sorted, xs,
      xa16, writes_off, cnt_w, w_sorted, meanA, N, nbWave);
  gemm_bf16<3, false, 2><<<GX * 2, 256, 0, stream>>>(
      xs, xp, meanA, BtW1, BtWr1, BtWl1, biasR1, pb, nullptr, N, HIDN);
  // layer 2
  agg_gcn<<<nbWave, 256, 0, stream>>>(pb, dinv, cites_off, deg_c, c_sorted, xs, N);
  gemm_bf16<3, false, 2><<<GX * 2, 256, 0, stream>>>(
      xs, pb, meanA, BtW2, BtWr2, BtWl2, biasR2, xp, nullptr, N, HIDN);
  // output projection: 3 col tiles of 128 (384 >= 349)
  gemm_bf16<1, true, 3><<<GX * 3, 256, 0, stream>>>(
      xp, nullptr, nullptr, BtLin, nullptr, nullptr, biasLin, nullptr, out, N, DOUT);
}

// Round 9
// 471.317 us; speedup vs baseline: 2.7485x; 1.0465x over previous
//
#include <hip/hip_runtime.h>

// HeteroGNN on MI355X — round 9: 8-deep gather ILP, 4B-packed sort tmp,
// single fused prep kernel. GEMMs unchanged from round 8 (proven shape).

#define DP   256
#define DA   128
#define HIDN 256
#define DOUT 349
#define NBKT 782          // ceil(100000/128)
#define CHUNK 4096

typedef unsigned short u16;
typedef unsigned int u32;
typedef __attribute__((ext_vector_type(8))) short bf16x8;
typedef __attribute__((ext_vector_type(4))) float f32x4;

__device__ __forceinline__ u16 bf16_rn(float x) {
  union { float f; unsigned u; } v; v.f = x;
  unsigned r = v.u + 0x7FFFu + ((v.u >> 16) & 1u);
  return (u16)(r >> 16);
}
__device__ __forceinline__ float bf16f(u16 h) {
  union { float f; unsigned u; } v; v.u = ((unsigned)h) << 16; return v.f;
}
__device__ __forceinline__ unsigned pack2(float a, float b) {
  return (unsigned)bf16_rn(a) | ((unsigned)bf16_rn(b) << 16);
}

__device__ __forceinline__ void gload16(const void* g, void* lds) {
  __builtin_amdgcn_global_load_lds(
      (const __attribute__((address_space(1))) unsigned int*)g,
      (__attribute__((address_space(3))) unsigned int*)lds, 16, 0, 0);
}

// ---------------- exclusive scan (2048/block) ----------------
#define SCAN_TPB 256
#define SCAN_VPT 8
#define SCAN_TILE 2048

__global__ void scan_local(const int* __restrict__ in, int* __restrict__ out,
                           int* __restrict__ bsum, int n) {
  __shared__ int sdata[SCAN_TPB];
  int t = threadIdx.x;
  int base = blockIdx.x * SCAN_TILE + t * SCAN_VPT;
  int v[SCAN_VPT];
  int sum = 0;
#pragma unroll
  for (int j = 0; j < SCAN_VPT; ++j) {
    int idx = base + j;
    v[j] = (idx < n) ? in[idx] : 0;
    sum += v[j];
  }
  sdata[t] = sum;
  __syncthreads();
  for (int off = 1; off < SCAN_TPB; off <<= 1) {
    int x = (t >= off) ? sdata[t - off] : 0;
    __syncthreads();
    sdata[t] += x;
    __syncthreads();
  }
  int prefix = sdata[t] - sum;
  if (t == SCAN_TPB - 1) bsum[blockIdx.x] = sdata[t];
  int run = prefix;
#pragma unroll
  for (int j = 0; j < SCAN_VPT; ++j) {
    int idx = base + j;
    if (idx < n) out[idx] = run;
    run += v[j];
  }
}

__global__ void scan_spine(int* __restrict__ bsum, int nb) {
  __shared__ int sdata[256];
  int t = threadIdx.x;
  int v = (t < nb) ? bsum[t] : 0;
  sdata[t] = v;
  __syncthreads();
  for (int off = 1; off < 256; off <<= 1) {
    int x = (t >= off) ? sdata[t - off] : 0;
    __syncthreads();
    sdata[t] += x;
    __syncthreads();
  }
  if (t < nb) bsum[t] = sdata[t] - v;
}

__global__ void scan_add(int* __restrict__ out, const int* __restrict__ bsum, int n) {
  int add = bsum[blockIdx.x];
  int base = blockIdx.x * SCAN_TILE + threadIdx.x * SCAN_VPT;
#pragma unroll
  for (int j = 0; j < SCAN_VPT; ++j) {
    int idx = base + j;
    if (idx < n) out[idx] += add;
  }
}

// -------- sort pass 1 (both edge types): chunk -> bucketed packed tmp (u32) ----
// tmp value = (src<<7) | (dst&127); bucket (dst>>7) implied by position.
__global__ __launch_bounds__(256) void sort_pass1(
    const int* __restrict__ c_src, const int* __restrict__ c_dst,
    const int* __restrict__ w_srcP, const int* __restrict__ w_dstP,
    u32* __restrict__ tmp, int* __restrict__ gcount, int* __restrict__ lofs,
    int E, int nch) {
  const int cg = blockIdx.x, t = threadIdx.x;
  const int et = cg >= nch;
  const int c = cg - et * nch;
  const int* src = et ? w_srcP : c_src;
  const int* dst = et ? w_dstP : c_dst;
  __shared__ u32 cnt[NBKT];
  __shared__ u32 ofs[NBKT];
  __shared__ u32 sdata[256];
  __shared__ u32 pay[CHUNK];   // 16KB
  __shared__ u16 bkt[CHUNK];   // 8KB

  for (int i = t; i < NBKT; i += 256) cnt[i] = 0;
  __syncthreads();
  const int base = c * CHUNK;
#pragma unroll
  for (int j = 0; j < 16; ++j) {
    int i = t + j * 256, idx = base + i;
    if (idx < E) {
      u32 s = (u32)src[idx], d = (u32)dst[idx];
      pay[i] = (s << 7) | (d & 127u);
      bkt[i] = (u16)(d >> 7);
      atomicAdd(&cnt[d >> 7], 1u);
    }
  }
  __syncthreads();
  for (int i = t; i < NBKT; i += 256)
    gcount[((size_t)et * NBKT + i) * nch + c] = (int)cnt[i];
  u32 ssum = 0;
  const int b0 = t * 4;
#pragma unroll
  for (int j = 0; j < 4; ++j) {
    int i = b0 + j;
    if (i < NBKT) ssum += cnt[i];
  }
  sdata[t] = ssum;
  __syncthreads();
  for (int o = 1; o < 256; o <<= 1) {
    u32 x = (t >= o) ? sdata[t - o] : 0;
    __syncthreads();
    sdata[t] += x;
    __syncthreads();
  }
  u32 run = sdata[t] - ssum;
#pragma unroll
  for (int j = 0; j < 4; ++j) {
    int i = b0 + j;
    if (i < NBKT) { ofs[i] = run; run += cnt[i]; }
  }
  __syncthreads();
  for (int i = t; i < NBKT; i += 256) {
    lofs[((size_t)et * nch + c) * NBKT + i] = (int)ofs[i];
    cnt[i] = ofs[i];
  }
  __syncthreads();
  u32* tout = tmp + (size_t)et * nch * CHUNK + base;
#pragma unroll
  for (int j = 0; j < 16; ++j) {
    int i = t + j * 256, idx = base + i;
    if (idx < E) {
      u32 p = atomicAdd(&cnt[bkt[i]], 1u);
      tout[p] = pay[i];
    }
  }
}

// -------- sort pass 2 (both edge types): bucket -> sorted + deg + off (+dinv) ---
#define MAXB 2560
__global__ __launch_bounds__(256) void sort_pass2(
    const u32* __restrict__ tmp, const int* __restrict__ prefix,
    const int* __restrict__ gcount, const int* __restrict__ lofs,
    int* __restrict__ cSorted, int* __restrict__ cDeg, int* __restrict__ cOff,
    int* __restrict__ wSorted, int* __restrict__ wDeg, int* __restrict__ wOff,
    float* __restrict__ dinv,
    int E, int nch, int n, int nbk) {
  const int bg = blockIdx.x, t = threadIdx.x;
  const int et = bg >= nbk;
  const int b = bg - et * nbk;
  int* outSorted = et ? wSorted : cSorted;
  int* deg = et ? wDeg : cDeg;
  int* offArr = et ? wOff : cOff;
  __shared__ u32 est[MAXB];
  __shared__ u32 outl[MAXB];
  __shared__ u32 cnt[128], ofs[128];
  __shared__ u32 sdata[256];

  const int node0 = b << 7;
  const size_t bgl = (size_t)et * NBKT + b;
  const int ebaseG = prefix[bgl * nch];
  const int eendG = (bg == 2 * nbk - 1) ? 2 * E : prefix[(bgl + 1) * nch];
  const int ebase = ebaseG - et * E;
  const int esize = (eendG - et * E) - ebase;

  const u32* tsrc = tmp + (size_t)et * nch * CHUNK;
  for (int c = t; c < nch; c += 256) {
    int g = lofs[((size_t)et * nch + c) * NBKT + b];
    int len = gcount[bgl * nch + c];
    int dp = prefix[bgl * nch + c] - ebaseG;
    for (int k = 0; k < len; ++k)
      est[dp + k] = tsrc[(size_t)c * CHUNK + g + k];
  }
  if (t < 128) cnt[t] = 0;
  __syncthreads();
  for (int i = t; i < esize; i += 256) atomicAdd(&cnt[est[i] & 127u], 1u);
  __syncthreads();
  u32 v = (t < 128) ? cnt[t] : 0;
  sdata[t] = v;
  __syncthreads();
  for (int o = 1; o < 256; o <<= 1) {
    u32 x = (t >= o) ? sdata[t - o] : 0;
    __syncthreads();
    sdata[t] += x;
    __syncthreads();
  }
  if (t < 128) ofs[t] = sdata[t] - v;
  __syncthreads();
  const int nNodes = (n - node0) < 128 ? (n - node0) : 128;
  if (t < nNodes) {
    deg[node0 + t] = (int)cnt[t];
    offArr[node0 + t] = ebase + (int)ofs[t];
    if (et == 0) dinv[node0 + t] = rsqrtf((float)(cnt[t] + 1));
  }
  __syncthreads();
  if (t < 128) cnt[t] = ofs[t];
  __syncthreads();
  for (int i = t; i < esize; i += 256) {
    u32 e = est[i];
    u32 p = atomicAdd(&cnt[e & 127u], 1u);
    outl[p] = e >> 7;
  }
  __syncthreads();
  for (int i = t; i < esize; i += 256) outSorted[ebase + i] = (int)outl[i];
}

// ---------------- fused prep: convs + weight transposes + biases ----------------
// Region table (blocks): [0,R1) conv x_paper; [R1,R2) conv x_author;
// [R2..] 7 weight preps; last block: biases.
__global__ void prep_all(
    const float* __restrict__ x_paper, const float* __restrict__ x_author,
    u16* __restrict__ xp, u16* __restrict__ xa16,
    const float* __restrict__ W1, const float* __restrict__ Wr1,
    const float* __restrict__ W2, const float* __restrict__ Wr2,
    const float* __restrict__ Wl1, const float* __restrict__ Wl2,
    const float* __restrict__ linW,
    u16* __restrict__ BtW1, u16* __restrict__ BtWr1,
    u16* __restrict__ BtW2, u16* __restrict__ BtWr2,
    u16* __restrict__ BtWl1, u16* __restrict__ BtWl2, u16* __restrict__ BtLin,
    const float* __restrict__ b1, const float* __restrict__ bl1,
    const float* __restrict__ b2, const float* __restrict__ bl2,
    const float* __restrict__ linb,
    float* __restrict__ biasR1, float* __restrict__ biasR2,
    float* __restrict__ biasLin,
    int N, int NA) {
  const int R1 = (N * 32 + 255) / 256;          // conv x_paper (8 f32/thread)
  const int R2 = R1 + (NA * 16 + 255) / 256;    // conv x_author
  const int WB = 256 * 256 / 256;               // 256 blocks per 256x256 weight
  const int LB = 256 * 128 / 256;               // 128 blocks per 128->256 weight
  const int FB = 384 * 256 / 256;               // 384 blocks for linW
  int bid = blockIdx.x, t = threadIdx.x;

  if (bid < R1) {
    int i = bid * 256 + t;
    if (i < N * 32) {
      const float4* x4 = (const float4*)x_paper;
      float4 v0 = x4[(size_t)i * 2];
      float4 v1 = x4[(size_t)i * 2 + 1];
      uint4 O;
      O.x = pack2(v0.x, v0.y); O.y = pack2(v0.z, v0.w);
      O.z = pack2(v1.x, v1.y); O.w = pack2(v1.z, v1.w);
      ((uint4*)xp)[i] = O;
    }
    return;
  }
  if (bid < R2) {
    int i = (bid - R1) * 256 + t;
    if (i < NA * 16) {
      const float4* x4 = (const float4*)x_author;
      float4 v0 = x4[(size_t)i * 2];
      float4 v1 = x4[(size_t)i * 2 + 1];
      uint4 O;
      O.x = pack2(v0.x, v0.y); O.y = pack2(v0.z, v0.w);
      O.z = pack2(v1.x, v1.y); O.w = pack2(v1.z, v1.w);
      ((uint4*)xa16)[i] = O;
    }
    return;
  }
  int wb = bid - R2;
  const float* W; u16* Bt; int K, Nn, Npad;
  if      (wb < WB)                  { W = W1;  Bt = BtW1;  K = 256; Nn = 256; Npad = 256; }
  else if ((wb -= WB) < WB)          { W = Wr1; Bt = BtWr1; K = 256; Nn = 256; Npad = 256; }
  else if ((wb -= WB) < WB)          { W = W2;  Bt = BtW2;  K = 256; Nn = 256; Npad = 256; }
  else if ((wb -= WB) < WB)          { W = Wr2; Bt = BtWr2; K = 256; Nn = 256; Npad = 256; }
  else if ((wb -= WB) < LB)          { W = Wl1; Bt = BtWl1; K = 128; Nn = 256; Npad = 256; }
  else if ((wb -= LB) < LB)          { W = Wl2; Bt = BtWl2; K = 128; Nn = 256; Npad = 256; }
  else if ((wb -= LB) < FB)          { W = linW; Bt = BtLin; K = 256; Nn = DOUT; Npad = 384; }
  else {
    // biases (single trailing block)
    if (t < 256) {
      biasR1[t] = b1[t] + bl1[t];
      biasR2[t] = b2[t] + bl2[t];
    }
    for (int i = t; i < 384; i += 256) biasLin[i] = (i < DOUT) ? linb[i] : 0.f;
    return;
  }
  int idx = wb * 256 + t;
  int tot = Npad * K;
  if (idx >= tot) return;
  int nn = idx / K, k = idx - nn * K;
  float v = (nn < Nn) ? W[(size_t)k * Nn + nn] : 0.f;
  Bt[idx] = bf16_rn(v);
}

// ---- 8-deep unrolled gather bodies --------------------------------------------
__device__ __forceinline__ void agg_body(
    const uint2* __restrict__ base, const float* __restrict__ dinv,
    const int* __restrict__ c_off, const int* __restrict__ c_cnt,
    const int* __restrict__ c_sorted, u16* __restrict__ xout,
    int d, int lane) {
  int start = c_off[d], cnt = c_cnt[d];
  float a0 = 0.f, a1 = 0.f, a2 = 0.f, a3 = 0.f;
  for (int j0 = 0; j0 < cnt; j0 += 64) {
    int nn = cnt - j0; nn = nn < 64 ? nn : 64;
    int sl = (j0 + lane < cnt) ? c_sorted[start + j0 + lane] : 0;
    int jj = 0;
    for (; jj + 8 <= nn; jj += 8) {
      int ss[8]; float dv[8]; uint2 vv[8];
#pragma unroll
      for (int u = 0; u < 8; ++u) ss[u] = __shfl(sl, jj + u);
#pragma unroll
      for (int u = 0; u < 8; ++u) dv[u] = dinv[ss[u]];
#pragma unroll
      for (int u = 0; u < 8; ++u) vv[u] = base[(size_t)ss[u] * 64 + lane];
#pragma unroll
      for (int u = 0; u < 8; ++u) {
        a0 = fmaf(bf16f((u16)vv[u].x), dv[u], a0);
        a1 = fmaf(bf16f((u16)(vv[u].x >> 16)), dv[u], a1);
        a2 = fmaf(bf16f((u16)vv[u].y), dv[u], a2);
        a3 = fmaf(bf16f((u16)(vv[u].y >> 16)), dv[u], a3);
      }
    }
    for (; jj < nn; ++jj) {
      int s = __shfl(sl, jj);
      float ds = dinv[s];
      uint2 v = base[(size_t)s * 64 + lane];
      a0 = fmaf(bf16f((u16)v.x), ds, a0); a1 = fmaf(bf16f((u16)(v.x >> 16)), ds, a1);
      a2 = fmaf(bf16f((u16)v.y), ds, a2); a3 = fmaf(bf16f((u16)(v.y >> 16)), ds, a3);
    }
  }
  float dd = dinv[d];
  {
    uint2 v = base[(size_t)d * 64 + lane];
    a0 = fmaf(bf16f((u16)v.x), dd, a0); a1 = fmaf(bf16f((u16)(v.x >> 16)), dd, a1);
    a2 = fmaf(bf16f((u16)v.y), dd, a2); a3 = fmaf(bf16f((u16)(v.y >> 16)), dd, a3);
  }
  uint2 O;
  O.x = pack2(a0 * dd, a1 * dd);
  O.y = pack2(a2 * dd, a3 * dd);
  ((uint2*)xout)[(size_t)d * 64 + lane] = O;
}

__device__ __forceinline__ void mean_body(
    const unsigned* __restrict__ xa, const int* __restrict__ w_off,
    const int* __restrict__ w_cnt, const int* __restrict__ w_sorted,
    u16* __restrict__ mean, int d, int lane) {
  int start = w_off[d];
  int cnt = w_cnt[d];
  float ax = 0.f, ay = 0.f;
  for (int j0 = 0; j0 < cnt; j0 += 64) {
    int nn = cnt - j0; nn = nn < 64 ? nn : 64;
    int sl = (j0 + lane < cnt) ? w_sorted[start + j0 + lane] : 0;
    int jj = 0;
    for (; jj + 8 <= nn; jj += 8) {
      int ss[8]; unsigned vv[8];
#pragma unroll
      for (int u = 0; u < 8; ++u) ss[u] = __shfl(sl, jj + u);
#pragma unroll
      for (int u = 0; u < 8; ++u) vv[u] = xa[(size_t)ss[u] * 64 + lane];
#pragma unroll
      for (int u = 0; u < 8; ++u) {
        ax += bf16f((u16)vv[u]);
        ay += bf16f((u16)(vv[u] >> 16));
      }
    }
    for (; jj < nn; ++jj) {
      int s = __shfl(sl, jj);
      unsigned v = xa[(size_t)s * 64 + lane];
      ax += bf16f((u16)v);
      ay += bf16f((u16)(v >> 16));
    }
  }
  float inv = 1.0f / (float)((cnt > 0) ? cnt : 1);
  ((unsigned*)mean)[(size_t)d * 64 + lane] = pack2(ax * inv, ay * inv);
}

// -------- fused gather: blocks [0,nbw) = cites agg; [nbw,2*nbw) = author mean --
__global__ void gather_fused(
    const u16* __restrict__ xin, const float* __restrict__ dinv,
    const int* __restrict__ c_off, const int* __restrict__ c_cnt,
    const int* __restrict__ c_sorted, u16* __restrict__ xout,
    const u16* __restrict__ xa16, const int* __restrict__ w_off,
    const int* __restrict__ w_cnt, const int* __restrict__ w_sorted,
    u16* __restrict__ mean, int n, int nbw) {
  const int lane = threadIdx.x & 63;
  if (blockIdx.x < nbw) {
    int d = ((blockIdx.x * blockDim.x) >> 6) + (threadIdx.x >> 6);
    if (d >= n) return;
    agg_body((const uint2*)xin, dinv, c_off, c_cnt, c_sorted, xout, d, lane);
  } else {
    int d = (((blockIdx.x - nbw) * blockDim.x) >> 6) + (threadIdx.x >> 6);
    if (d >= n) return;
    mean_body((const unsigned*)xa16, w_off, w_cnt, w_sorted, mean, d, lane);
  }
}

// ---------------- agg_gcn standalone (layer 2) ----------------
__global__ void agg_gcn(const u16* __restrict__ xin, const float* __restrict__ dinv,
                        const int* __restrict__ c_off, const int* __restrict__ c_cnt,
                        const int* __restrict__ c_sorted,
                        u16* __restrict__ xout, int n) {
  int d = (blockIdx.x * blockDim.x + threadIdx.x) >> 6;
  int lane = threadIdx.x & 63;
  if (d >= n) return;
  agg_body((const uint2*)xin, dinv, c_off, c_cnt, c_sorted, xout, d, lane);
}

// ------------- bf16 MFMA GEMM: tile 128x128, 4 waves (2x2), 32KB LDS ----------
template <int NSEG, bool F32OUT, int NC>
__global__ __launch_bounds__(256, 4) void gemm_bf16(
    const u16* __restrict__ A0, const u16* __restrict__ A1, const u16* __restrict__ A2,
    const u16* __restrict__ B0, const u16* __restrict__ B1, const u16* __restrict__ B2,
    const float* __restrict__ bias,
    u16* __restrict__ Cp, float* __restrict__ Cf,
    int M, int N) {
  __shared__ u16 Ah[2][4096];   // 128 rows x 32 k
  __shared__ u16 Bh[2][4096];   // 128 cols x 32 k

  const int t = threadIdx.x;
  const int wid = t >> 6, lane = t & 63;
  const int wr = wid >> 1, wc = wid & 1;
  const int lrow = lane & 15, kslot = lane >> 4;
  const int jsw = kslot ^ ((lrow >> 1) & 3);

  const int nb = gridDim.x;
  const int q = nb >> 3, r = nb & 7;
  const int xcd = blockIdx.x & 7, pos = blockIdx.x >> 3;
  const int lin = (xcd < r ? xcd * (q + 1) : r * (q + 1) + (xcd - r) * q) + pos;
  const int bx = lin / NC, by = lin - bx * NC;
  const int gm = bx * 128;
  const int gn = by * 128;

  const int s_r = lane >> 2;
  const int s_j = (lane & 3) ^ ((s_r >> 1) & 3);

  f32x4 acc[4][4];
  const f32x4 z4 = {0.f, 0.f, 0.f, 0.f};
#pragma unroll
  for (int m = 0; m < 4; ++m)
#pragma unroll
    for (int n = 0; n < 4; ++n) acc[m][n] = z4;

  const int NT = (NSEG == 3) ? 20 : 8;

  auto STAGE = [&](int tt, int half) {
    const u16* A;
    const u16* B;
    int rs, k0;
    if (NSEG == 3 && tt >= 16)     { A = A2; B = B2; rs = 128; k0 = (tt - 16) * 32; }
    else if (NSEG == 3 && tt >= 8) { A = A1; B = B1; rs = 256; k0 = (tt - 8) * 32; }
    else                           { A = A0; B = B0; rs = 256; k0 = tt * 32; }
    const int c = wid * 2;
#pragma unroll
    for (int cc = 0; cc < 2; ++cc) {
      int grow = gm + (c + cc) * 16 + s_r;
      grow = grow < M ? grow : M - 1;
      gload16(A + (size_t)grow * rs + (k0 + s_j * 8), &Ah[half][(c + cc) * 512]);
      int col = gn + (c + cc) * 16 + s_r;
      gload16(B + (size_t)col * rs + (k0 + s_j * 8), &Bh[half][(c + cc) * 512]);
    }
  };

  STAGE(0, 0);
  __syncthreads();

  for (int tt = 0; tt < NT; ++tt) {
    const int half = tt & 1;
    if (tt + 1 < NT) STAGE(tt + 1, half ^ 1);

    bf16x8 ah[4];
    const int ab = (wr * 64 + lrow) * 32 + jsw * 8;
#pragma unroll
    for (int m = 0; m < 4; ++m) ah[m] = *(const bf16x8*)&Ah[half][ab + m * 512];
    const int bb = (wc * 64 + lrow) * 32 + jsw * 8;
#pragma unroll
    for (int n = 0; n < 4; ++n) {
      bf16x8 bn = *(const bf16x8*)&Bh[half][bb + n * 512];
#pragma unroll
      for (int m = 0; m < 4; ++m)
        acc[m][n] = __builtin_amdgcn_mfma_f32_16x16x32_bf16(ah[m], bn, acc[m][n], 0, 0, 0);
    }
    __syncthreads();
  }

  const int col0 = gn + wc * 64 + lrow;
  const int row00 = gm + wr * 64 + kslot * 4;
#pragma unroll
  for (int m = 0; m < 4; ++m) {
#pragma unroll
    for (int i = 0; i < 4; ++i) {
      int row = row00 + m * 16 + i;
      if (row >= M) continue;
#pragma unroll
      for (int n = 0; n < 4; ++n) {
        int col = col0 + n * 16;
        float v = acc[m][n][i] + bias[col];
        if (F32OUT) {
          if (col < N) Cf[(size_t)row * N + col] = v;
        } else {
          Cp[(size_t)row * 256 + col] = bf16_rn(fmaxf(v, 0.f));
        }
      }
    }
  }
}

// ---------------- launch ----------------
static inline size_t align_up(size_t x) { return (x + 255) & ~(size_t)255; }

extern "C" void kernel_launch(void* const* d_in, const int* in_sizes, int n_in,
                              void* d_out, int out_size, void* d_ws, size_t ws_size,
                              hipStream_t stream) {
  const float* x_paper  = (const float*)d_in[0];
  const float* x_author = (const float*)d_in[1];
  const int*   cites    = (const int*)d_in[2];
  const int*   w_src    = (const int*)d_in[3];
  const int*   w_dst    = (const int*)d_in[4];
  const float* W1  = (const float*)d_in[5];
  const float* b1  = (const float*)d_in[6];
  const float* Wl1 = (const float*)d_in[7];
  const float* bl1 = (const float*)d_in[8];
  const float* Wr1 = (const float*)d_in[9];
  const float* W2  = (const float*)d_in[10];
  const float* b2  = (const float*)d_in[11];
  const float* Wl2 = (const float*)d_in[12];
  const float* bl2 = (const float*)d_in[13];
  const float* Wr2 = (const float*)d_in[14];
  const float* linW = (const float*)d_in[15];
  const float* linb = (const float*)d_in[16];
  float* out = (float*)d_out;

  const int N = in_sizes[0] / DP;       // 100000
  const int NA = in_sizes[1] / DA;      // 50000
  const int E = in_sizes[3];            // 1000000
  const int* c_src = cites;
  const int* c_dst = cites + E;

  const int NCH = (E + CHUNK - 1) / CHUNK;       // 245
  const int NB = (N + 127) >> 7;                 // 782
  const int GC2 = 2 * NB * NCH;

  char* w = (char*)d_ws;
  size_t off = 0;
  auto alloc = [&](size_t bytes) -> void* {
    void* p = w + off;
    off = align_up(off + bytes);
    return p;
  };
  int* deg_c      = (int*)alloc((size_t)N * 4);
  int* cnt_w      = (int*)alloc((size_t)N * 4);
  int* cites_off  = (int*)alloc((size_t)N * 4);
  int* writes_off = (int*)alloc((size_t)N * 4);
  int* c_sorted   = (int*)alloc((size_t)E * 4);
  int* w_sorted   = (int*)alloc((size_t)E * 4);
  u32* tmpE       = (u32*)alloc((size_t)2 * NCH * CHUNK * 4);
  int* gcount     = (int*)alloc((size_t)GC2 * 4);
  int* gprefix    = (int*)alloc((size_t)GC2 * 4);
  int* lofs       = (int*)alloc((size_t)2 * NCH * NBKT * 4);
  int* bsumA      = (int*)alloc(256 * 4);
  float* dinv     = (float*)alloc((size_t)N * 4);
  u16* xa16       = (u16*)alloc((size_t)NA * DA * 2);
  u16* meanA      = (u16*)alloc((size_t)N * DA * 2);
  u16* xp         = (u16*)alloc((size_t)N * 256 * 2);
  u16* xs         = (u16*)alloc((size_t)N * 256 * 2);
  u16* pb         = (u16*)alloc((size_t)N * 256 * 2);
  const int bsW = 256 * 256, bsL = 256 * 128, bsLin = 384 * 256;
  u16* BtW1  = (u16*)alloc((size_t)bsW * 2);
  u16* BtWr1 = (u16*)alloc((size_t)bsW * 2);
  u16* BtW2  = (u16*)alloc((size_t)bsW * 2);
  u16* BtWr2 = (u16*)alloc((size_t)bsW * 2);
  u16* BtWl1 = (u16*)alloc((size_t)bsL * 2);
  u16* BtWl2 = (u16*)alloc((size_t)bsL * 2);
  u16* BtLin = (u16*)alloc((size_t)bsLin * 2);
  float* biasR1  = (float*)alloc(256 * 4);
  float* biasR2  = (float*)alloc(256 * 4);
  float* biasLin = (float*)alloc(384 * 4);
  (void)ws_size; (void)n_in; (void)out_size;

  const int nsb2 = (GC2 + SCAN_TILE - 1) / SCAN_TILE;

  // ---- fused CSR build (both edge types) ----
  sort_pass1<<<2 * NCH, 256, 0, stream>>>(c_src, c_dst, w_src, w_dst,
                                          tmpE, gcount, lofs, E, NCH);
  scan_local<<<nsb2, SCAN_TPB, 0, stream>>>(gcount, gprefix, bsumA, GC2);
  scan_spine<<<1, 256, 0, stream>>>(bsumA, nsb2);
  scan_add<<<nsb2, SCAN_TPB, 0, stream>>>(gprefix, bsumA, GC2);
  sort_pass2<<<2 * NB, 256, 0, stream>>>(tmpE, gprefix, gcount, lofs,
                                         c_sorted, deg_c, cites_off,
                                         w_sorted, cnt_w, writes_off,
                                         dinv, E, NCH, N, NB);

  // ---- fused prep (convs + weights + biases) ----
  {
    const int R1 = (N * 32 + 255) / 256;
    const int R2 = R1 + (NA * 16 + 255) / 256;
    const int total = R2 + 4 * 256 + 2 * 128 + 384 + 1;
    prep_all<<<total, 256, 0, stream>>>(
        x_paper, x_author, xp, xa16,
        W1, Wr1, W2, Wr2, Wl1, Wl2, linW,
        BtW1, BtWr1, BtW2, BtWr2, BtWl1, BtWl2, BtLin,
        b1, bl1, b2, bl2, linb, biasR1, biasR2, biasLin, N, NA);
  }

  const int nbWave = (N * 64 + 255) / 256;
  const int GX = (N + 127) / 128;  // 782

  // layer 1: fused agg(cites) + author-mean
  gather_fused<<<2 * nbWave, 256, 0, stream>>>(
      xp, dinv, cites_off, deg_c, c_sorted, xs,
      xa16, writes_off, cnt_w, w_sorted, meanA, N, nbWave);
  gemm_bf16<3, false, 2><<<GX * 2, 256, 0, stream>>>(
      xs, xp, meanA, BtW1, BtWr1, BtWl1, biasR1, pb, nullptr, N, HIDN);
  // layer 2
  agg_gcn<<<nbWave, 256, 0, stream>>>(pb, dinv, cites_off, deg_c, c_sorted, xs, N);
  gemm_bf16<3, false, 2><<<GX * 2, 256, 0, stream>>>(
      xs, pb, meanA, BtW2, BtWr2, BtWl2, biasR2, xp, nullptr, N, HIDN);
  // output projection: 3 col tiles of 128 (384 >= 349)
  gemm_bf16<1, true, 3><<<GX * 3, 256, 0, stream>>>(
      xp, nullptr, nullptr, BtLin, nullptr, nullptr, biasLin, nullptr, out, N, DOUT);
}

// Round 10
// 460.875 us; speedup vs baseline: 2.8108x; 1.0227x over previous
//
#include <hip/hip_runtime.h>

// HeteroGNN on MI355X — round 10: wide-transaction gathers.
//   cites agg: 32 lanes x 16B per row, 2 edges/wave (halves), shfl_xor(32) merge
//   author mean: 16 lanes x 16B per row, 4 edges/wave (quarters)
//   rest (sort, prep_all, 128x128 GEMMs) unchanged from round 9.

#define DP   256
#define DA   128
#define HIDN 256
#define DOUT 349
#define NBKT 782          // ceil(100000/128)
#define CHUNK 4096

typedef unsigned short u16;
typedef unsigned int u32;
typedef __attribute__((ext_vector_type(8))) short bf16x8;
typedef __attribute__((ext_vector_type(4))) float f32x4;

__device__ __forceinline__ u16 bf16_rn(float x) {
  union { float f; unsigned u; } v; v.f = x;
  unsigned r = v.u + 0x7FFFu + ((v.u >> 16) & 1u);
  return (u16)(r >> 16);
}
__device__ __forceinline__ float bf16f(u16 h) {
  union { float f; unsigned u; } v; v.u = ((unsigned)h) << 16; return v.f;
}
__device__ __forceinline__ unsigned pack2(float a, float b) {
  return (unsigned)bf16_rn(a) | ((unsigned)bf16_rn(b) << 16);
}

__device__ __forceinline__ void gload16(const void* g, void* lds) {
  __builtin_amdgcn_global_load_lds(
      (const __attribute__((address_space(1))) unsigned int*)g,
      (__attribute__((address_space(3))) unsigned int*)lds, 16, 0, 0);
}

// ---------------- exclusive scan (2048/block) ----------------
#define SCAN_TPB 256
#define SCAN_VPT 8
#define SCAN_TILE 2048

__global__ void scan_local(const int* __restrict__ in, int* __restrict__ out,
                           int* __restrict__ bsum, int n) {
  __shared__ int sdata[SCAN_TPB];
  int t = threadIdx.x;
  int base = blockIdx.x * SCAN_TILE + t * SCAN_VPT;
  int v[SCAN_VPT];
  int sum = 0;
#pragma unroll
  for (int j = 0; j < SCAN_VPT; ++j) {
    int idx = base + j;
    v[j] = (idx < n) ? in[idx] : 0;
    sum += v[j];
  }
  sdata[t] = sum;
  __syncthreads();
  for (int off = 1; off < SCAN_TPB; off <<= 1) {
    int x = (t >= off) ? sdata[t - off] : 0;
    __syncthreads();
    sdata[t] += x;
    __syncthreads();
  }
  int prefix = sdata[t] - sum;
  if (t == SCAN_TPB - 1) bsum[blockIdx.x] = sdata[t];
  int run = prefix;
#pragma unroll
  for (int j = 0; j < SCAN_VPT; ++j) {
    int idx = base + j;
    if (idx < n) out[idx] = run;
    run += v[j];
  }
}

__global__ void scan_spine(int* __restrict__ bsum, int nb) {
  __shared__ int sdata[256];
  int t = threadIdx.x;
  int v = (t < nb) ? bsum[t] : 0;
  sdata[t] = v;
  __syncthreads();
  for (int off = 1; off < 256; off <<= 1) {
    int x = (t >= off) ? sdata[t - off] : 0;
    __syncthreads();
    sdata[t] += x;
    __syncthreads();
  }
  if (t < nb) bsum[t] = sdata[t] - v;
}

__global__ void scan_add(int* __restrict__ out, const int* __restrict__ bsum, int n) {
  int add = bsum[blockIdx.x];
  int base = blockIdx.x * SCAN_TILE + threadIdx.x * SCAN_VPT;
#pragma unroll
  for (int j = 0; j < SCAN_VPT; ++j) {
    int idx = base + j;
    if (idx < n) out[idx] += add;
  }
}

// -------- sort pass 1 (both edge types): chunk -> bucketed packed tmp (u32) ----
__global__ __launch_bounds__(256) void sort_pass1(
    const int* __restrict__ c_src, const int* __restrict__ c_dst,
    const int* __restrict__ w_srcP, const int* __restrict__ w_dstP,
    u32* __restrict__ tmp, int* __restrict__ gcount, int* __restrict__ lofs,
    int E, int nch) {
  const int cg = blockIdx.x, t = threadIdx.x;
  const int et = cg >= nch;
  const int c = cg - et * nch;
  const int* src = et ? w_srcP : c_src;
  const int* dst = et ? w_dstP : c_dst;
  __shared__ u32 cnt[NBKT];
  __shared__ u32 ofs[NBKT];
  __shared__ u32 sdata[256];
  __shared__ u32 pay[CHUNK];
  __shared__ u16 bkt[CHUNK];

  for (int i = t; i < NBKT; i += 256) cnt[i] = 0;
  __syncthreads();
  const int base = c * CHUNK;
#pragma unroll
  for (int j = 0; j < 16; ++j) {
    int i = t + j * 256, idx = base + i;
    if (idx < E) {
      u32 s = (u32)src[idx], d = (u32)dst[idx];
      pay[i] = (s << 7) | (d & 127u);
      bkt[i] = (u16)(d >> 7);
      atomicAdd(&cnt[d >> 7], 1u);
    }
  }
  __syncthreads();
  for (int i = t; i < NBKT; i += 256)
    gcount[((size_t)et * NBKT + i) * nch + c] = (int)cnt[i];
  u32 ssum = 0;
  const int b0 = t * 4;
#pragma unroll
  for (int j = 0; j < 4; ++j) {
    int i = b0 + j;
    if (i < NBKT) ssum += cnt[i];
  }
  sdata[t] = ssum;
  __syncthreads();
  for (int o = 1; o < 256; o <<= 1) {
    u32 x = (t >= o) ? sdata[t - o] : 0;
    __syncthreads();
    sdata[t] += x;
    __syncthreads();
  }
  u32 run = sdata[t] - ssum;
#pragma unroll
  for (int j = 0; j < 4; ++j) {
    int i = b0 + j;
    if (i < NBKT) { ofs[i] = run; run += cnt[i]; }
  }
  __syncthreads();
  for (int i = t; i < NBKT; i += 256) {
    lofs[((size_t)et * nch + c) * NBKT + i] = (int)ofs[i];
    cnt[i] = ofs[i];
  }
  __syncthreads();
  u32* tout = tmp + (size_t)et * nch * CHUNK + base;
#pragma unroll
  for (int j = 0; j < 16; ++j) {
    int i = t + j * 256, idx = base + i;
    if (idx < E) {
      u32 p = atomicAdd(&cnt[bkt[i]], 1u);
      tout[p] = pay[i];
    }
  }
}

// -------- sort pass 2 (both edge types): bucket -> sorted + deg + off (+dinv) ---
#define MAXB 2560
__global__ __launch_bounds__(256) void sort_pass2(
    const u32* __restrict__ tmp, const int* __restrict__ prefix,
    const int* __restrict__ gcount, const int* __restrict__ lofs,
    int* __restrict__ cSorted, int* __restrict__ cDeg, int* __restrict__ cOff,
    int* __restrict__ wSorted, int* __restrict__ wDeg, int* __restrict__ wOff,
    float* __restrict__ dinv,
    int E, int nch, int n, int nbk) {
  const int bg = blockIdx.x, t = threadIdx.x;
  const int et = bg >= nbk;
  const int b = bg - et * nbk;
  int* outSorted = et ? wSorted : cSorted;
  int* deg = et ? wDeg : cDeg;
  int* offArr = et ? wOff : cOff;
  __shared__ u32 est[MAXB];
  __shared__ u32 outl[MAXB];
  __shared__ u32 cnt[128], ofs[128];
  __shared__ u32 sdata[256];

  const int node0 = b << 7;
  const size_t bgl = (size_t)et * NBKT + b;
  const int ebaseG = prefix[bgl * nch];
  const int eendG = (bg == 2 * nbk - 1) ? 2 * E : prefix[(bgl + 1) * nch];
  const int ebase = ebaseG - et * E;
  const int esize = (eendG - et * E) - ebase;

  const u32* tsrc = tmp + (size_t)et * nch * CHUNK;
  for (int c = t; c < nch; c += 256) {
    int g = lofs[((size_t)et * nch + c) * NBKT + b];
    int len = gcount[bgl * nch + c];
    int dp = prefix[bgl * nch + c] - ebaseG;
    for (int k = 0; k < len; ++k)
      est[dp + k] = tsrc[(size_t)c * CHUNK + g + k];
  }
  if (t < 128) cnt[t] = 0;
  __syncthreads();
  for (int i = t; i < esize; i += 256) atomicAdd(&cnt[est[i] & 127u], 1u);
  __syncthreads();
  u32 v = (t < 128) ? cnt[t] : 0;
  sdata[t] = v;
  __syncthreads();
  for (int o = 1; o < 256; o <<= 1) {
    u32 x = (t >= o) ? sdata[t - o] : 0;
    __syncthreads();
    sdata[t] += x;
    __syncthreads();
  }
  if (t < 128) ofs[t] = sdata[t] - v;
  __syncthreads();
  const int nNodes = (n - node0) < 128 ? (n - node0) : 128;
  if (t < nNodes) {
    deg[node0 + t] = (int)cnt[t];
    offArr[node0 + t] = ebase + (int)ofs[t];
    if (et == 0) dinv[node0 + t] = rsqrtf((float)(cnt[t] + 1));
  }
  __syncthreads();
  if (t < 128) cnt[t] = ofs[t];
  __syncthreads();
  for (int i = t; i < esize; i += 256) {
    u32 e = est[i];
    u32 p = atomicAdd(&cnt[e & 127u], 1u);
    outl[p] = e >> 7;
  }
  __syncthreads();
  for (int i = t; i < esize; i += 256) outSorted[ebase + i] = (int)outl[i];
}

// ---------------- fused prep: convs + weight transposes + biases ----------------
__global__ void prep_all(
    const float* __restrict__ x_paper, const float* __restrict__ x_author,
    u16* __restrict__ xp, u16* __restrict__ xa16,
    const float* __restrict__ W1, const float* __restrict__ Wr1,
    const float* __restrict__ W2, const float* __restrict__ Wr2,
    const float* __restrict__ Wl1, const float* __restrict__ Wl2,
    const float* __restrict__ linW,
    u16* __restrict__ BtW1, u16* __restrict__ BtWr1,
    u16* __restrict__ BtW2, u16* __restrict__ BtWr2,
    u16* __restrict__ BtWl1, u16* __restrict__ BtWl2, u16* __restrict__ BtLin,
    const float* __restrict__ b1, const float* __restrict__ bl1,
    const float* __restrict__ b2, const float* __restrict__ bl2,
    const float* __restrict__ linb,
    float* __restrict__ biasR1, float* __restrict__ biasR2,
    float* __restrict__ biasLin,
    int N, int NA) {
  const int R1 = (N * 32 + 255) / 256;
  const int R2 = R1 + (NA * 16 + 255) / 256;
  const int WB = 256 * 256 / 256;
  const int LB = 256 * 128 / 256;
  const int FB = 384 * 256 / 256;
  int bid = blockIdx.x, t = threadIdx.x;

  if (bid < R1) {
    int i = bid * 256 + t;
    if (i < N * 32) {
      const float4* x4 = (const float4*)x_paper;
      float4 v0 = x4[(size_t)i * 2];
      float4 v1 = x4[(size_t)i * 2 + 1];
      uint4 O;
      O.x = pack2(v0.x, v0.y); O.y = pack2(v0.z, v0.w);
      O.z = pack2(v1.x, v1.y); O.w = pack2(v1.z, v1.w);
      ((uint4*)xp)[i] = O;
    }
    return;
  }
  if (bid < R2) {
    int i = (bid - R1) * 256 + t;
    if (i < NA * 16) {
      const float4* x4 = (const float4*)x_author;
      float4 v0 = x4[(size_t)i * 2];
      float4 v1 = x4[(size_t)i * 2 + 1];
      uint4 O;
      O.x = pack2(v0.x, v0.y); O.y = pack2(v0.z, v0.w);
      O.z = pack2(v1.x, v1.y); O.w = pack2(v1.z, v1.w);
      ((uint4*)xa16)[i] = O;
    }
    return;
  }
  int wb = bid - R2;
  const float* W; u16* Bt; int K, Nn, Npad;
  if      (wb < WB)                  { W = W1;  Bt = BtW1;  K = 256; Nn = 256; Npad = 256; }
  else if ((wb -= WB) < WB)          { W = Wr1; Bt = BtWr1; K = 256; Nn = 256; Npad = 256; }
  else if ((wb -= WB) < WB)          { W = W2;  Bt = BtW2;  K = 256; Nn = 256; Npad = 256; }
  else if ((wb -= WB) < WB)          { W = Wr2; Bt = BtWr2; K = 256; Nn = 256; Npad = 256; }
  else if ((wb -= WB) < LB)          { W = Wl1; Bt = BtWl1; K = 128; Nn = 256; Npad = 256; }
  else if ((wb -= LB) < LB)          { W = Wl2; Bt = BtWl2; K = 128; Nn = 256; Npad = 256; }
  else if ((wb -= LB) < FB)          { W = linW; Bt = BtLin; K = 256; Nn = DOUT; Npad = 384; }
  else {
    if (t < 256) {
      biasR1[t] = b1[t] + bl1[t];
      biasR2[t] = b2[t] + bl2[t];
    }
    for (int i = t; i < 384; i += 256) biasLin[i] = (i < DOUT) ? linb[i] : 0.f;
    return;
  }
  int idx = wb * 256 + t;
  int tot = Npad * K;
  if (idx >= tot) return;
  int nn = idx / K, k = idx - nn * K;
  float v = (nn < Nn) ? W[(size_t)k * Nn + nn] : 0.f;
  Bt[idx] = bf16_rn(v);
}

// ---- wide gather bodies -------------------------------------------------------
// cites agg: row = 512B = 32 uint4; 32 lanes cover a row; 2 edges/wave (halves).
__device__ __forceinline__ void agg_body(
    const uint4* __restrict__ base, const float* __restrict__ dinv,
    const int* __restrict__ c_off, const int* __restrict__ c_cnt,
    const int* __restrict__ c_sorted, u16* __restrict__ xout,
    int d, int lane) {
  const int hl = lane & 31;
  const int half = lane >> 5;
  int start = c_off[d], cnt = c_cnt[d];
  float acc[8] = {};
  for (int j0 = 0; j0 < cnt; j0 += 64) {
    int nn = cnt - j0; nn = nn < 64 ? nn : 64;
    int sl = (j0 + lane < cnt) ? c_sorted[start + j0 + lane] : 0;
    int jj = 0;
    for (; jj + 8 <= nn; jj += 8) {  // 4 pairs = 8 edges
      int ss[4]; float dv[4]; uint4 vv[4];
#pragma unroll
      for (int u = 0; u < 4; ++u) ss[u] = __shfl(sl, jj + 2 * u + half);
#pragma unroll
      for (int u = 0; u < 4; ++u) dv[u] = dinv[ss[u]];
#pragma unroll
      for (int u = 0; u < 4; ++u) vv[u] = base[(size_t)ss[u] * 32 + hl];
#pragma unroll
      for (int u = 0; u < 4; ++u) {
        const u16* p = (const u16*)&vv[u];
#pragma unroll
        for (int e = 0; e < 8; ++e) acc[e] = fmaf(bf16f(p[e]), dv[u], acc[e]);
      }
    }
    for (; jj < nn; jj += 2) {  // pair tail, weight-masked
      int idx = jj + half;
      int s = __shfl(sl, idx < nn ? idx : jj);
      float wgt = (idx < nn) ? dinv[s] : 0.f;
      uint4 v = base[(size_t)s * 32 + hl];
      const u16* p = (const u16*)&v;
#pragma unroll
      for (int e = 0; e < 8; ++e) acc[e] = fmaf(bf16f(p[e]), wgt, acc[e]);
    }
  }
  float dd = dinv[d];
  {
    uint4 v = base[(size_t)d * 32 + hl];
    float wgt = half ? 0.f : dd;   // self row added once
    const u16* p = (const u16*)&v;
#pragma unroll
    for (int e = 0; e < 8; ++e) acc[e] = fmaf(bf16f(p[e]), wgt, acc[e]);
  }
  float f[8];
#pragma unroll
  for (int e = 0; e < 8; ++e) f[e] = (acc[e] + __shfl_xor(acc[e], 32)) * dd;
  if (lane < 32) {
    uint4 O;
    O.x = pack2(f[0], f[1]); O.y = pack2(f[2], f[3]);
    O.z = pack2(f[4], f[5]); O.w = pack2(f[6], f[7]);
    ((uint4*)xout)[(size_t)d * 32 + hl] = O;
  }
}

// author mean: row = 256B = 16 uint4; 16 lanes cover a row; 4 edges/wave.
__device__ __forceinline__ void mean_body(
    const uint4* __restrict__ xa, const int* __restrict__ w_off,
    const int* __restrict__ w_cnt, const int* __restrict__ w_sorted,
    u16* __restrict__ mean, int d, int lane) {
  const int hl = lane & 15;
  const int qt = lane >> 4;
  int start = w_off[d], cnt = w_cnt[d];
  float acc[8] = {};
  for (int j0 = 0; j0 < cnt; j0 += 64) {
    int nn = cnt - j0; nn = nn < 64 ? nn : 64;
    int sl = (j0 + lane < cnt) ? w_sorted[start + j0 + lane] : 0;
    int jj = 0;
    for (; jj + 8 <= nn; jj += 8) {  // 2 quads = 8 edges
      int ss[2]; uint4 vv[2];
#pragma unroll
      for (int u = 0; u < 2; ++u) ss[u] = __shfl(sl, jj + 4 * u + qt);
#pragma unroll
      for (int u = 0; u < 2; ++u) vv[u] = xa[(size_t)ss[u] * 16 + hl];
#pragma unroll
      for (int u = 0; u < 2; ++u) {
        const u16* p = (const u16*)&vv[u];
#pragma unroll
        for (int e = 0; e < 8; ++e) acc[e] += bf16f(p[e]);
      }
    }
    for (; jj < nn; jj += 4) {  // quad tail, weight-masked
      int idx = jj + qt;
      int s = __shfl(sl, idx < nn ? idx : jj);
      float wgt = (idx < nn) ? 1.f : 0.f;
      uint4 v = xa[(size_t)s * 16 + hl];
      const u16* p = (const u16*)&v;
#pragma unroll
      for (int e = 0; e < 8; ++e) acc[e] = fmaf(bf16f(p[e]), wgt, acc[e]);
    }
  }
  float inv = 1.0f / (float)((cnt > 0) ? cnt : 1);
  float f[8];
#pragma unroll
  for (int e = 0; e < 8; ++e) {
    float x = acc[e] + __shfl_xor(acc[e], 16);
    x += __shfl_xor(x, 32);
    f[e] = x * inv;
  }
  if (lane < 16) {
    uint4 O;
    O.x = pack2(f[0], f[1]); O.y = pack2(f[2], f[3]);
    O.z = pack2(f[4], f[5]); O.w = pack2(f[6], f[7]);
    ((uint4*)mean)[(size_t)d * 16 + hl] = O;
  }
}

// -------- fused gather: blocks [0,nbw) = cites agg; [nbw,2*nbw) = author mean --
__global__ void gather_fused(
    const u16* __restrict__ xin, const float* __restrict__ dinv,
    const int* __restrict__ c_off, const int* __restrict__ c_cnt,
    const int* __restrict__ c_sorted, u16* __restrict__ xout,
    const u16* __restrict__ xa16, const int* __restrict__ w_off,
    const int* __restrict__ w_cnt, const int* __restrict__ w_sorted,
    u16* __restrict__ mean, int n, int nbw) {
  const int lane = threadIdx.x & 63;
  if (blockIdx.x < nbw) {
    int d = ((blockIdx.x * blockDim.x) >> 6) + (threadIdx.x >> 6);
    if (d >= n) return;
    agg_body((const uint4*)xin, dinv, c_off, c_cnt, c_sorted, xout, d, lane);
  } else {
    int d = (((blockIdx.x - nbw) * blockDim.x) >> 6) + (threadIdx.x >> 6);
    if (d >= n) return;
    mean_body((const uint4*)xa16, w_off, w_cnt, w_sorted, mean, d, lane);
  }
}

// ---------------- agg_gcn standalone (layer 2) ----------------
__global__ void agg_gcn(const u16* __restrict__ xin, const float* __restrict__ dinv,
                        const int* __restrict__ c_off, const int* __restrict__ c_cnt,
                        const int* __restrict__ c_sorted,
                        u16* __restrict__ xout, int n) {
  int d = (blockIdx.x * blockDim.x + threadIdx.x) >> 6;
  int lane = threadIdx.x & 63;
  if (d >= n) return;
  agg_body((const uint4*)xin, dinv, c_off, c_cnt, c_sorted, xout, d, lane);
}

// ------------- bf16 MFMA GEMM: tile 128x128, 4 waves (2x2), 32KB LDS ----------
template <int NSEG, bool F32OUT, int NC>
__global__ __launch_bounds__(256, 4) void gemm_bf16(
    const u16* __restrict__ A0, const u16* __restrict__ A1, const u16* __restrict__ A2,
    const u16* __restrict__ B0, const u16* __restrict__ B1, const u16* __restrict__ B2,
    const float* __restrict__ bias,
    u16* __restrict__ Cp, float* __restrict__ Cf,
    int M, int N) {
  __shared__ u16 Ah[2][4096];
  __shared__ u16 Bh[2][4096];

  const int t = threadIdx.x;
  const int wid = t >> 6, lane = t & 63;
  const int wr = wid >> 1, wc = wid & 1;
  const int lrow = lane & 15, kslot = lane >> 4;
  const int jsw = kslot ^ ((lrow >> 1) & 3);

  const int nb = gridDim.x;
  const int q = nb >> 3, r = nb & 7;
  const int xcd = blockIdx.x & 7, pos = blockIdx.x >> 3;
  const int lin = (xcd < r ? xcd * (q + 1) : r * (q + 1) + (xcd - r) * q) + pos;
  const int bx = lin / NC, by = lin - bx * NC;
  const int gm = bx * 128;
  const int gn = by * 128;

  const int s_r = lane >> 2;
  const int s_j = (lane & 3) ^ ((s_r >> 1) & 3);

  f32x4 acc[4][4];
  const f32x4 z4 = {0.f, 0.f, 0.f, 0.f};
#pragma unroll
  for (int m = 0; m < 4; ++m)
#pragma unroll
    for (int n = 0; n < 4; ++n) acc[m][n] = z4;

  const int NT = (NSEG == 3) ? 20 : 8;

  auto STAGE = [&](int tt, int half) {
    const u16* A;
    const u16* B;
    int rs, k0;
    if (NSEG == 3 && tt >= 16)     { A = A2; B = B2; rs = 128; k0 = (tt - 16) * 32; }
    else if (NSEG == 3 && tt >= 8) { A = A1; B = B1; rs = 256; k0 = (tt - 8) * 32; }
    else                           { A = A0; B = B0; rs = 256; k0 = tt * 32; }
    const int c = wid * 2;
#pragma unroll
    for (int cc = 0; cc < 2; ++cc) {
      int grow = gm + (c + cc) * 16 + s_r;
      grow = grow < M ? grow : M - 1;
      gload16(A + (size_t)grow * rs + (k0 + s_j * 8), &Ah[half][(c + cc) * 512]);
      int col = gn + (c + cc) * 16 + s_r;
      gload16(B + (size_t)col * rs + (k0 + s_j * 8), &Bh[half][(c + cc) * 512]);
    }
  };

  STAGE(0, 0);
  __syncthreads();

  for (int tt = 0; tt < NT; ++tt) {
    const int half = tt & 1;
    if (tt + 1 < NT) STAGE(tt + 1, half ^ 1);

    bf16x8 ah[4];
    const int ab = (wr * 64 + lrow) * 32 + jsw * 8;
#pragma unroll
    for (int m = 0; m < 4; ++m) ah[m] = *(const bf16x8*)&Ah[half][ab + m * 512];
    const int bb = (wc * 64 + lrow) * 32 + jsw * 8;
#pragma unroll
    for (int n = 0; n < 4; ++n) {
      bf16x8 bn = *(const bf16x8*)&Bh[half][bb + n * 512];
#pragma unroll
      for (int m = 0; m < 4; ++m)
        acc[m][n] = __builtin_amdgcn_mfma_f32_16x16x32_bf16(ah[m], bn, acc[m][n], 0, 0, 0);
    }
    __syncthreads();
  }

  const int col0 = gn + wc * 64 + lrow;
  const int row00 = gm + wr * 64 + kslot * 4;
#pragma unroll
  for (int m = 0; m < 4; ++m) {
#pragma unroll
    for (int i = 0; i < 4; ++i) {
      int row = row00 + m * 16 + i;
      if (row >= M) continue;
#pragma unroll
      for (int n = 0; n < 4; ++n) {
        int col = col0 + n * 16;
        float v = acc[m][n][i] + bias[col];
        if (F32OUT) {
          if (col < N) Cf[(size_t)row * N + col] = v;
        } else {
          Cp[(size_t)row * 256 + col] = bf16_rn(fmaxf(v, 0.f));
        }
      }
    }
  }
}

// ---------------- launch ----------------
static inline size_t align_up(size_t x) { return (x + 255) & ~(size_t)255; }

extern "C" void kernel_launch(void* const* d_in, const int* in_sizes, int n_in,
                              void* d_out, int out_size, void* d_ws, size_t ws_size,
                              hipStream_t stream) {
  const float* x_paper  = (const float*)d_in[0];
  const float* x_author = (const float*)d_in[1];
  const int*   cites    = (const int*)d_in[2];
  const int*   w_src    = (const int*)d_in[3];
  const int*   w_dst    = (const int*)d_in[4];
  const float* W1  = (const float*)d_in[5];
  const float* b1  = (const float*)d_in[6];
  const float* Wl1 = (const float*)d_in[7];
  const float* bl1 = (const float*)d_in[8];
  const float* Wr1 = (const float*)d_in[9];
  const float* W2  = (const float*)d_in[10];
  const float* b2  = (const float*)d_in[11];
  const float* Wl2 = (const float*)d_in[12];
  const float* bl2 = (const float*)d_in[13];
  const float* Wr2 = (const float*)d_in[14];
  const float* linW = (const float*)d_in[15];
  const float* linb = (const float*)d_in[16];
  float* out = (float*)d_out;

  const int N = in_sizes[0] / DP;       // 100000
  const int NA = in_sizes[1] / DA;      // 50000
  const int E = in_sizes[3];            // 1000000
  const int* c_src = cites;
  const int* c_dst = cites + E;

  const int NCH = (E + CHUNK - 1) / CHUNK;       // 245
  const int NB = (N + 127) >> 7;                 // 782
  const int GC2 = 2 * NB * NCH;

  char* w = (char*)d_ws;
  size_t off = 0;
  auto alloc = [&](size_t bytes) -> void* {
    void* p = w + off;
    off = align_up(off + bytes);
    return p;
  };
  int* deg_c      = (int*)alloc((size_t)N * 4);
  int* cnt_w      = (int*)alloc((size_t)N * 4);
  int* cites_off  = (int*)alloc((size_t)N * 4);
  int* writes_off = (int*)alloc((size_t)N * 4);
  int* c_sorted   = (int*)alloc((size_t)E * 4);
  int* w_sorted   = (int*)alloc((size_t)E * 4);
  u32* tmpE       = (u32*)alloc((size_t)2 * NCH * CHUNK * 4);
  int* gcount     = (int*)alloc((size_t)GC2 * 4);
  int* gprefix    = (int*)alloc((size_t)GC2 * 4);
  int* lofs       = (int*)alloc((size_t)2 * NCH * NBKT * 4);
  int* bsumA      = (int*)alloc(256 * 4);
  float* dinv     = (float*)alloc((size_t)N * 4);
  u16* xa16       = (u16*)alloc((size_t)NA * DA * 2);
  u16* meanA      = (u16*)alloc((size_t)N * DA * 2);
  u16* xp         = (u16*)alloc((size_t)N * 256 * 2);
  u16* xs         = (u16*)alloc((size_t)N * 256 * 2);
  u16* pb         = (u16*)alloc((size_t)N * 256 * 2);
  const int bsW = 256 * 256, bsL = 256 * 128, bsLin = 384 * 256;
  u16* BtW1  = (u16*)alloc((size_t)bsW * 2);
  u16* BtWr1 = (u16*)alloc((size_t)bsW * 2);
  u16* BtW2  = (u16*)alloc((size_t)bsW * 2);
  u16* BtWr2 = (u16*)alloc((size_t)bsW * 2);
  u16* BtWl1 = (u16*)alloc((size_t)bsL * 2);
  u16* BtWl2 = (u16*)alloc((size_t)bsL * 2);
  u16* BtLin = (u16*)alloc((size_t)bsLin * 2);
  float* biasR1  = (float*)alloc(256 * 4);
  float* biasR2  = (float*)alloc(256 * 4);
  float* biasLin = (float*)alloc(384 * 4);
  (void)ws_size; (void)n_in; (void)out_size;

  const int nsb2 = (GC2 + SCAN_TILE - 1) / SCAN_TILE;

  // ---- fused CSR build (both edge types) ----
  sort_pass1<<<2 * NCH, 256, 0, stream>>>(c_src, c_dst, w_src, w_dst,
                                          tmpE, gcount, lofs, E, NCH);
  scan_local<<<nsb2, SCAN_TPB, 0, stream>>>(gcount, gprefix, bsumA, GC2);
  scan_spine<<<1, 256, 0, stream>>>(bsumA, nsb2);
  scan_add<<<nsb2, SCAN_TPB, 0, stream>>>(gprefix, bsumA, GC2);
  sort_pass2<<<2 * NB, 256, 0, stream>>>(tmpE, gprefix, gcount, lofs,
                                         c_sorted, deg_c, cites_off,
                                         w_sorted, cnt_w, writes_off,
                                         dinv, E, NCH, N, NB);

  // ---- fused prep (convs + weights + biases) ----
  {
    const int R1 = (N * 32 + 255) / 256;
    const int R2 = R1 + (NA * 16 + 255) / 256;
    const int total = R2 + 4 * 256 + 2 * 128 + 384 + 1;
    prep_all<<<total, 256, 0, stream>>>(
        x_paper, x_author, xp, xa16,
        W1, Wr1, W2, Wr2, Wl1, Wl2, linW,
        BtW1, BtWr1, BtW2, BtWr2, BtWl1, BtWl2, BtLin,
        b1, bl1, b2, bl2, linb, biasR1, biasR2, biasLin, N, NA);
  }

  const int nbWave = (N * 64 + 255) / 256;
  const int GX = (N + 127) / 128;  // 782

  // layer 1: fused agg(cites) + author-mean
  gather_fused<<<2 * nbWave, 256, 0, stream>>>(
      xp, dinv, cites_off, deg_c, c_sorted, xs,
      xa16, writes_off, cnt_w, w_sorted, meanA, N, nbWave);
  gemm_bf16<3, false, 2><<<GX * 2, 256, 0, stream>>>(
      xs, xp, meanA, BtW1, BtWr1, BtWl1, biasR1, pb, nullptr, N, HIDN);
  // layer 2
  agg_gcn<<<nbWave, 256, 0, stream>>>(pb, dinv, cites_off, deg_c, c_sorted, xs, N);
  gemm_bf16<3, false, 2><<<GX * 2, 256, 0, stream>>>(
      xs, pb, meanA, BtW2, BtWr2, BtWl2, biasR2, xp, nullptr, N, HIDN);
  // output projection: 3 col tiles of 128 (384 >= 349)
  gemm_bf16<1, true, 3><<<GX * 3, 256, 0, stream>>>(
      xp, nullptr, nullptr, BtLin, nullptr, nullptr, biasLin, nullptr, out, N, DOUT);
}